// Round 9
// baseline (1426.479 us; speedup 1.0000x reference)
//
#include <hip/hip_runtime.h>
#include <math.h>

#define D_DIM    2048
#define BT_DIM   16384   // B*T
#define NSLOTS   4096
#define NTILES   32      // NSLOTS / 128
#define SCALE    0.02209708691207961f  // 1/sqrt(2048)
#define MARGIN   0.02f
#define CAND_MAX 16
#define KSPLIT   4

typedef __attribute__((ext_vector_type(8))) short bf16x8;
typedef __attribute__((ext_vector_type(4))) float f32x4;
typedef __attribute__((ext_vector_type(8))) unsigned short u16x8;
typedef __attribute__((ext_vector_type(4))) unsigned short u16x4;

__device__ __forceinline__ unsigned short f2bf(float f) {
    unsigned int u = __float_as_uint(f);
    return (unsigned short)((u + 0x7fffu + ((u >> 16) & 1u)) >> 16);
}
__device__ __forceinline__ float bf2f(unsigned short s) {
    return __uint_as_float(((unsigned int)s) << 16);
}

__device__ __forceinline__ void async_cp16(const void* g, void* l) {
    __builtin_amdgcn_global_load_lds(
        (const __attribute__((address_space(1))) void*)g,
        (__attribute__((address_space(3))) void*)l, 16, 0, 0);
}

// ---------------------------------------------------------------------------
// top-4 helpers (jax semantics: val desc, idx asc) -- used in refine merge
// ---------------------------------------------------------------------------
__device__ __forceinline__ bool cand_better(float v, int i, float v2, int i2) {
    return (v > v2) || (v == v2 && i < i2);
}

__device__ __forceinline__ void cand_insert(float v, int idx,
                                            float& v0, int& i0, float& v1, int& i1,
                                            float& v2, int& i2, float& v3, int& i3) {
    if (cand_better(v, idx, v3, i3)) {
        if (cand_better(v, idx, v0, i0)) {
            v3 = v2; i3 = i2; v2 = v1; i2 = i1; v1 = v0; i1 = i0; v0 = v; i0 = idx;
        } else if (cand_better(v, idx, v1, i1)) {
            v3 = v2; i3 = i2; v2 = v1; i2 = i1; v1 = v; i1 = idx;
        } else if (cand_better(v, idx, v2, i2)) {
            v3 = v2; i3 = i2; v2 = v; i2 = idx;
        } else {
            v3 = v; i3 = idx;
        }
    }
}

// ---------------------------------------------------------------------------
// Fused: KW partials GEMM (z<4) + bf16 conversions (z==4).
// GEMM: Cpart[z] = A[M,Kc] @ B[Kc,N], BIT-EXACT per-thread FMA order vs
// rounds 2-8 (k ascending, lacc fold every 16). Round-9: BK=32 halves the
// barrier count (r8 showed barriers, not conflicts/latency, are the cost).
// The z==4 slice streams x/sv/wout -> bf16 under the VALU-bound GEMM
// (8% HBM there -- conversions ride along ~free).
// ---------------------------------------------------------------------------
__global__ __launch_bounds__(256)
void gemm_kw_fused(const float* __restrict__ A, const float* __restrict__ B,
                   float* __restrict__ Cpart, int M, int N, int K,
                   const float* __restrict__ x,  unsigned short* __restrict__ xb,
                   const float* __restrict__ sv, unsigned short* __restrict__ svb,
                   const float* __restrict__ wo, unsigned short* __restrict__ wob) {
    __shared__ float As[32][132];   // [k][m], padded (132%32==4 -> 4-way max)
    __shared__ float Bs[32][132];   // [k][n], padded

    const int tid = threadIdx.x;

    if (blockIdx.z == KSPLIT) {
        // ---------------- conversion slice: 512 blocks x 256 threads -------
        const int  flat  = blockIdx.y * gridDim.x + blockIdx.x;   // 0..511
        const long tid8  = (long)flat * 256 + tid;                 // chunk id
        const long nthr  = 512L * 256;                             // 131072
        // x: 33.55M elems = 4.19M chunks of 8 -> 32 iters
        for (long c = tid8; c < 4194304L; c += nthr) {
            const size_t i = (size_t)c * 8;
            float4 a = *(const float4*)(x + i);
            float4 b = *(const float4*)(x + i + 4);
            u16x8 o;
            o[0] = f2bf(a.x); o[1] = f2bf(a.y); o[2] = f2bf(a.z); o[3] = f2bf(a.w);
            o[4] = f2bf(b.x); o[5] = f2bf(b.y); o[6] = f2bf(b.z); o[7] = f2bf(b.w);
            *(u16x8*)(xb + i) = o;
        }
        // sv: 8.39M elems = 1.05M chunks -> 8 iters
        for (long c = tid8; c < 1048576L; c += nthr) {
            const size_t i = (size_t)c * 8;
            float4 a = *(const float4*)(sv + i);
            float4 b = *(const float4*)(sv + i + 4);
            u16x8 o;
            o[0] = f2bf(a.x); o[1] = f2bf(a.y); o[2] = f2bf(a.z); o[3] = f2bf(a.w);
            o[4] = f2bf(b.x); o[5] = f2bf(b.y); o[6] = f2bf(b.z); o[7] = f2bf(b.w);
            *(u16x8*)(svb + i) = o;
        }
        // wout: 4.19M elems = 524288 chunks -> 4 iters
        for (long c = tid8; c < 524288L; c += nthr) {
            const size_t i = (size_t)c * 8;
            float4 a = *(const float4*)(wo + i);
            float4 b = *(const float4*)(wo + i + 4);
            u16x8 o;
            o[0] = f2bf(a.x); o[1] = f2bf(a.y); o[2] = f2bf(a.z); o[3] = f2bf(a.w);
            o[4] = f2bf(b.x); o[5] = f2bf(b.y); o[6] = f2bf(b.z); o[7] = f2bf(b.w);
            *(u16x8*)(wob + i) = o;
        }
        return;
    }

    // ---------------- GEMM slice (z < 4) ----------------
    const int bm  = blockIdx.y * 128;
    const int bn  = blockIdx.x * 128;
    const int kc  = K / KSPLIT;
    const int ks  = blockIdx.z * kc;
    float* C = Cpart + (size_t)blockIdx.z * M * N;
    const int ty  = tid >> 4;
    const int tx  = tid & 15;

    float acc[2][2][4][4];
#pragma unroll
    for (int rb = 0; rb < 2; ++rb)
#pragma unroll
        for (int cb = 0; cb < 2; ++cb)
#pragma unroll
            for (int i = 0; i < 4; ++i)
#pragma unroll
                for (int j = 0; j < 4; ++j) acc[rb][cb][i][j] = 0.0f;

    for (int k0 = ks; k0 < ks + kc; k0 += 32) {
        // stage 128x32 A and 32x128 B (4 float4 per thread each)
#pragma unroll
        for (int h = 0; h < 4; ++h) {
            const int p = tid + h * 256;          // 0..1023 float4 id
            const int rowA = p >> 3;              // 0..127
            const int kkA  = (p & 7) << 2;        // 0,4,..,28
            float4 a4 = *(const float4*)(A + (size_t)(bm + rowA) * K + (k0 + kkA));
            As[kkA + 0][rowA] = a4.x;
            As[kkA + 1][rowA] = a4.y;
            As[kkA + 2][rowA] = a4.z;
            As[kkA + 3][rowA] = a4.w;
            const int kB = p >> 5;                // 0..31
            const int n4 = (p & 31) << 2;         // 0,4,..,124
            float4 b4 = *(const float4*)(B + (size_t)(k0 + kB) * N + (bn + n4));
            *(float4*)&Bs[kB][n4] = b4;
        }
        __syncthreads();

#pragma unroll
        for (int kb = 0; kb < 2; ++kb) {
            float lacc[2][2][4][4];
#pragma unroll
            for (int rb = 0; rb < 2; ++rb)
#pragma unroll
                for (int cb = 0; cb < 2; ++cb)
#pragma unroll
                    for (int i = 0; i < 4; ++i)
#pragma unroll
                        for (int j = 0; j < 4; ++j) lacc[rb][cb][i][j] = 0.0f;

#pragma unroll
            for (int k = kb * 16; k < kb * 16 + 16; ++k) {
                float a[2][4], b[2][4];
#pragma unroll
                for (int h = 0; h < 2; ++h) {
                    *(float4*)a[h] = *(const float4*)&As[k][h * 64 + ty * 4];
                    *(float4*)b[h] = *(const float4*)&Bs[k][h * 64 + tx * 4];
                }
#pragma unroll
                for (int rb = 0; rb < 2; ++rb)
#pragma unroll
                    for (int cb = 0; cb < 2; ++cb)
#pragma unroll
                        for (int i = 0; i < 4; ++i)
#pragma unroll
                            for (int j = 0; j < 4; ++j)
                                lacc[rb][cb][i][j] =
                                    fmaf(a[rb][i], b[cb][j], lacc[rb][cb][i][j]);
            }
#pragma unroll
            for (int rb = 0; rb < 2; ++rb)
#pragma unroll
                for (int cb = 0; cb < 2; ++cb)
#pragma unroll
                    for (int i = 0; i < 4; ++i)
#pragma unroll
                        for (int j = 0; j < 4; ++j)
                            acc[rb][cb][i][j] += lacc[rb][cb][i][j];
        }
        __syncthreads();
    }

#pragma unroll
    for (int rb = 0; rb < 2; ++rb)
#pragma unroll
        for (int i = 0; i < 4; ++i) {
            const size_t r = (size_t)(bm + rb * 64 + ty * 4 + i);
#pragma unroll
            for (int cb = 0; cb < 2; ++cb) {
                float4 o;
                o.x = acc[rb][cb][i][0];
                o.y = acc[rb][cb][i][1];
                o.z = acc[rb][cb][i][2];
                o.w = acc[rb][cb][i][3];
                *(float4*)(C + r * N + (bn + cb * 64 + tx * 4)) = o;
            }
        }
}

// ---------------------------------------------------------------------------
// KW = sum of 4 K-chunk partials (deterministic); also emit kwb = bf16(KW).
// ---------------------------------------------------------------------------
__global__ __launch_bounds__(256)
void reduce_kw(const float* __restrict__ part, float* __restrict__ KW,
               unsigned short* __restrict__ kwb) {
    const size_t i = ((size_t)blockIdx.x * 256 + threadIdx.x) * 4;
    const size_t stride = (size_t)NSLOTS * D_DIM;
    float4 s0 = *(const float4*)(part + i);
    float4 s1 = *(const float4*)(part + i + stride);
    float4 s2 = *(const float4*)(part + i + 2 * stride);
    float4 s3 = *(const float4*)(part + i + 3 * stride);
    float4 o;
    o.x = (s0.x + s1.x) + (s2.x + s3.x);
    o.y = (s0.y + s1.y) + (s2.y + s3.y);
    o.z = (s0.z + s1.z) + (s2.z + s3.z);
    o.w = (s0.w + s1.w) + (s2.w + s3.w);
    *(float4*)(KW + i) = o;
    u16x4 b;
    b[0] = f2bf(o.x); b[1] = f2bf(o.y); b[2] = f2bf(o.z); b[3] = f2bf(o.w);
    *(u16x4*)(kwb + i) = b;
}

// ---------------------------------------------------------------------------
// bf16 MFMA GEMM: C[M,N] = A[M,K] @ B[N,K]^T; C fp32 or bf16 (template).
// m97 structure, PURE, NO swizzle (r8: swizzle cost ~45us, L3-resident data).
// ---------------------------------------------------------------------------
template <bool BF16_OUT>
__global__ __launch_bounds__(256)
void gemm_bf16_abt(const unsigned short* __restrict__ A,
                   const unsigned short* __restrict__ B,
                   void* __restrict__ Cv, int M, int N, int K) {
    __shared__ __align__(16) unsigned short Alds[128 * 32];
    __shared__ __align__(16) unsigned short Blds[128 * 32];

    const int tid  = threadIdx.x;
    const int lane = tid & 63;
    const int w    = tid >> 6;
    const int wr   = w >> 1, wc = w & 1;
    const int bm   = blockIdx.y * 128;
    const int bn   = blockIdx.x * 128;

    const int srow = lane >> 2;
    const int skch = (lane & 3) ^ ((lane >> 3) & 3);
    const int c0 = w, c1 = w + 4;
    const unsigned short* gA0 = A + (size_t)(bm + c0 * 16 + srow) * K + skch * 8;
    const unsigned short* gA1 = A + (size_t)(bm + c1 * 16 + srow) * K + skch * 8;
    const unsigned short* gB0 = B + (size_t)(bn + c0 * 16 + srow) * K + skch * 8;
    const unsigned short* gB1 = B + (size_t)(bn + c1 * 16 + srow) * K + skch * 8;
    char* lA0 = (char*)Alds + c0 * 1024;
    char* lA1 = (char*)Alds + c1 * 1024;
    char* lB0 = (char*)Blds + c0 * 1024;
    char* lB1 = (char*)Blds + c1 * 1024;

    const int kbyte = (((lane >> 4) ^ ((lane >> 1) & 3)) << 4);
    const int rA = wr * 64 + (lane & 15);
    const int rB = wc * 64 + (lane & 15);

    f32x4 acc[4][4] = {};

    for (int kt = 0; kt < K; kt += 32) {
        async_cp16(gA0, lA0);
        async_cp16(gA1, lA1);
        async_cp16(gB0, lB0);
        async_cp16(gB1, lB1);
        gA0 += 32; gA1 += 32; gB0 += 32; gB1 += 32;
        __syncthreads();

        bf16x8 a[4], b[4];
#pragma unroll
        for (int i = 0; i < 4; ++i) {
            a[i] = *(const bf16x8*)((const char*)Alds + (rA + i * 16) * 64 + kbyte);
            b[i] = *(const bf16x8*)((const char*)Blds + (rB + i * 16) * 64 + kbyte);
        }
#pragma unroll
        for (int i = 0; i < 4; ++i)
#pragma unroll
            for (int j = 0; j < 4; ++j)
                acc[i][j] = __builtin_amdgcn_mfma_f32_16x16x32_bf16(
                    a[i], b[j], acc[i][j], 0, 0, 0);
        __syncthreads();
    }

    const int orow = (lane >> 4) * 4;
    const int ocol = lane & 15;
#pragma unroll
    for (int i = 0; i < 4; ++i)
#pragma unroll
        for (int j = 0; j < 4; ++j) {
            const size_t base =
                (size_t)(bm + wr * 64 + i * 16 + orow) * N + (bn + wc * 64 + j * 16 + ocol);
#pragma unroll
            for (int r = 0; r < 4; ++r) {
                if constexpr (BF16_OUT)
                    ((unsigned short*)Cv)[base + (size_t)r * N] = f2bf(acc[i][j][r]);
                else
                    ((float*)Cv)[base + (size_t)r * N] = acc[i][j][r];
            }
        }
}

// ---------------------------------------------------------------------------
// Streaming per-tile top-4 -- branchless packed-key argmax (r7, validated).
// ---------------------------------------------------------------------------
__global__ __launch_bounds__(256)
void aux_pass(const unsigned short* __restrict__ scoresb,
              float4* __restrict__ aux) {
    const int tid  = threadIdx.x;
    const int lane = tid & 63;
    const int w    = tid >> 6;
    const int t    = blockIdx.x * 4 + w;
    const unsigned short* srow = scoresb + (size_t)t * NSLOTS;

#pragma unroll
    for (int j = 0; j < 8; ++j) {
        const int c0 = j * 512 + lane * 8;   // tile = j*4 + (lane>>4)
        const u16x8 s8 = *(const u16x8*)(srow + c0);
        unsigned int k[8];
#pragma unroll
        for (int e = 0; e < 8; ++e) {
            const unsigned int b   = (unsigned int)s8[e] & 0xffffu;
            const unsigned int ord = b ^ ((b & 0x8000u) ? 0xffffu : 0x8000u);
            k[e] = (ord << 12) | (4095u - (unsigned int)(c0 + e));
        }
        unsigned int win[4];
#pragma unroll
        for (int p = 0; p < 4; ++p) {
            unsigned int m01 = max(k[0], k[1]), m23 = max(k[2], k[3]);
            unsigned int m45 = max(k[4], k[5]), m67 = max(k[6], k[7]);
            unsigned int m = max(max(m01, m23), max(m45, m67));
#pragma unroll
            for (int off = 1; off < 16; off <<= 1)
                m = max(m, (unsigned int)__shfl_xor((int)m, off));
            win[p] = m;
#pragma unroll
            for (int e = 0; e < 8; ++e) k[e] = (k[e] == m) ? 0u : k[e];
        }
        if ((lane & 15) == 0) {
            float vv[4]; int id[4];
#pragma unroll
            for (int p = 0; p < 4; ++p) {
                const unsigned int ord = win[p] >> 12;
                const unsigned int b =
                    (ord & 0x8000u) ? (ord ^ 0x8000u) : (~ord & 0xffffu);
                vv[p] = bf2f((unsigned short)b);
                id[p] = 4095 - (int)(win[p] & 0xfffu);
            }
            const int tile = j * 4 + (lane >> 4);
            float4* dst = aux + ((size_t)t * NTILES + tile) * 2;
            float4 o1, o2;
            o1.x = vv[0]; o1.y = __int_as_float(id[0]);
            o1.z = vv[1]; o1.w = __int_as_float(id[1]);
            o2.x = vv[2]; o2.y = __int_as_float(id[2]);
            o2.z = vv[3]; o2.w = __int_as_float(id[3]);
            dst[0] = o1;
            dst[1] = o2;
        }
    }
}

// ---------------------------------------------------------------------------
// Wave-per-row refine: merge aux -> thresh -> candidates (aux + rare flagged
// tile rescan) -> EXACT fp32 re-score (identical math, rounds 2-8) ->
// softmax -> gather.
// ---------------------------------------------------------------------------
__global__ __launch_bounds__(256)
void topk_refine(const float4* __restrict__ aux,
                 const unsigned short* __restrict__ scoresb,
                 const float* __restrict__ x,
                 const float* __restrict__ KW,
                 const unsigned short* __restrict__ svb,
                 unsigned short* __restrict__ retr) {
    const int tid  = threadIdx.x;
    const int lane = tid & 63;
    const int w    = tid >> 6;
    const int t    = blockIdx.x * 4 + w;

    const float* xrow = x + (size_t)t * D_DIM + lane * 4;
    float4 xv[8];
#pragma unroll
    for (int i = 0; i < 8; ++i) xv[i] = *(const float4*)(xrow + 256 * i);

    __shared__ int          cand[4][CAND_MAX];
    __shared__ int          ncand[4];
    __shared__ unsigned int flags[4];
    if (lane == 0) { ncand[w] = 0; flags[w] = 0; }
    __syncthreads();

    const float4 e2 = aux[(size_t)t * 64 + lane];
    float v0 = -INFINITY, v1 = -INFINITY, v2 = -INFINITY, v3 = -INFINITY;
    int   i0 = 0x7fffffff, i1 = 0x7fffffff, i2 = 0x7fffffff, i3 = 0x7fffffff;
    cand_insert(e2.x, __float_as_int(e2.y), v0, i0, v1, i1, v2, i2, v3, i3);
    cand_insert(e2.z, __float_as_int(e2.w), v0, i0, v1, i1, v2, i2, v3, i3);
#pragma unroll
    for (int off = 1; off < 64; off <<= 1) {
        float s0 = __shfl_xor(v0, off), s1 = __shfl_xor(v1, off);
        float s2 = __shfl_xor(v2, off), s3 = __shfl_xor(v3, off);
        int   j0 = __shfl_xor(i0, off), j1 = __shfl_xor(i1, off);
        int   j2 = __shfl_xor(i2, off), j3 = __shfl_xor(i3, off);
        cand_insert(s0, j0, v0, i0, v1, i1, v2, i2, v3, i3);
        cand_insert(s1, j1, v0, i0, v1, i1, v2, i2, v3, i3);
        cand_insert(s2, j2, v0, i0, v1, i1, v2, i2, v3, i3);
        cand_insert(s3, j3, v0, i0, v1, i1, v2, i2, v3, i3);
    }
    const float thresh = v3 - MARGIN;

    if ((lane & 1) && e2.z >= thresh)
        atomicOr(&flags[w], 1u << (lane >> 1));
    __syncthreads();
    const unsigned int fl = flags[w];

    const int mytile = lane >> 1;
    if (!((fl >> mytile) & 1u)) {
        if (e2.x >= thresh) {
            int p = atomicAdd(&ncand[w], 1);
            if (p < CAND_MAX) cand[w][p] = __float_as_int(e2.y);
        }
        if (e2.z >= thresh) {
            int p = atomicAdd(&ncand[w], 1);
            if (p < CAND_MAX) cand[w][p] = __float_as_int(e2.w);
        }
    }
    unsigned int fscan = fl;
    while (fscan) {
        const int tb = __ffs(fscan) - 1;
        fscan &= fscan - 1;
        const unsigned short* srow =
            scoresb + (size_t)t * NSLOTS + tb * 128 + lane * 2;
        const unsigned short s0 = srow[0], s1 = srow[1];
        if (bf2f(s0) >= thresh) {
            int p = atomicAdd(&ncand[w], 1);
            if (p < CAND_MAX) cand[w][p] = tb * 128 + lane * 2;
        }
        if (bf2f(s1) >= thresh) {
            int p = atomicAdd(&ncand[w], 1);
            if (p < CAND_MAX) cand[w][p] = tb * 128 + lane * 2 + 1;
        }
    }
    __syncthreads();
    const int nc = min(ncand[w], CAND_MAX);

    float r0 = -INFINITY, r1 = -INFINITY, r2 = -INFINITY, r3 = -INFINITY;
    int   q0 = 0x7fffffff, q1 = 0x7fffffff, q2 = 0x7fffffff, q3 = 0x7fffffff;
    for (int c = 0; c < nc; ++c) {
        const int slot = cand[w][c];
        const float* kr = KW + (size_t)slot * D_DIM + lane * 4;
        float p = 0.0f;
#pragma unroll
        for (int i = 0; i < 8; ++i) {
            const float4 k4 = *(const float4*)(kr + 256 * i);
            p = fmaf(xv[i].x, k4.x, p);
            p = fmaf(xv[i].y, k4.y, p);
            p = fmaf(xv[i].z, k4.z, p);
            p = fmaf(xv[i].w, k4.w, p);
        }
#pragma unroll
        for (int off = 1; off < 64; off <<= 1) p += __shfl_xor(p, off);
        cand_insert(p, slot, r0, q0, r1, q1, r2, q2, r3, q3);
    }

    const float e1s = expf(SCALE * (r1 - r0));
    const float e2s = expf(SCALE * (r2 - r0));
    const float e3s = expf(SCALE * (r3 - r0));
    const float inv = 1.0f / (1.0f + e1s + e2s + e3s);
    const float w0s = inv, w1s = e1s * inv, w2s = e2s * inv, w3s = e3s * inv;

    const unsigned short* p0 = svb + (size_t)q0 * D_DIM;
    const unsigned short* p1 = svb + (size_t)q1 * D_DIM;
    const unsigned short* p2 = svb + (size_t)q2 * D_DIM;
    const unsigned short* p3 = svb + (size_t)q3 * D_DIM;
    unsigned short* orow = retr + (size_t)t * D_DIM;
#pragma unroll
    for (int i = 0; i < 4; ++i) {
        const int d0 = lane * 8 + 512 * i;
        u16x8 a0 = *(const u16x8*)(p0 + d0);
        u16x8 a1 = *(const u16x8*)(p1 + d0);
        u16x8 a2 = *(const u16x8*)(p2 + d0);
        u16x8 a3 = *(const u16x8*)(p3 + d0);
        u16x8 o;
#pragma unroll
        for (int e = 0; e < 8; ++e) {
            float s = w0s * bf2f(a0[e]) + w1s * bf2f(a1[e]) +
                      w2s * bf2f(a2[e]) + w3s * bf2f(a3[e]);
            o[e] = f2bf(s);
        }
        *(u16x8*)(orow + d0) = o;
    }
}

// ---------------------------------------------------------------------------
extern "C" void kernel_launch(void* const* d_in, const int* in_sizes, int n_in,
                              void* d_out, int out_size, void* d_ws, size_t ws_size,
                              hipStream_t stream) {
    const float* x    = (const float*)d_in[0];
    const float* sk   = (const float*)d_in[1];
    const float* sv   = (const float*)d_in[2];
    const float* wq   = (const float*)d_in[3];
    const float* wout = (const float*)d_in[4];

    // workspace layout (293.6 MB; proven ws >= 402 MB)
    char* base = (char*)d_ws;
    float*          kwpart  = (float*)base;                       // 4 x 33.55 MB (then reused)
    unsigned short* scoresb = (unsigned short*)base;              // 134.2 MB (after reduce)
    float*          KW      = (float*)(base + 134217728);         //  33.55 MB
    unsigned short* kwb     = (unsigned short*)(base + 167772160);//  16.78 MB
    unsigned short* woutb   = (unsigned short*)(base + 184549376);//   8.39 MB
    unsigned short* xb      = (unsigned short*)(base + 192937984);//  67.11 MB (reused as retr)
    unsigned short* svb     = (unsigned short*)(base + 260046848);//  16.78 MB
    float4*         aux     = (float4*)(base + 276824064);        //  16.78 MB

    const dim3 blk(256);

    // KW partials (z<4) + x/sv/wout bf16 conversions (z==4), one dispatch
    gemm_kw_fused<<<dim3(D_DIM / 128, NSLOTS / 128, KSPLIT + 1), blk, 0, stream>>>(
        sk, wq, kwpart, NSLOTS, D_DIM, D_DIM,
        x, xb, sv, svb, wout, woutb);

    // KW = sum(partials); kwb = bf16(KW)
    reduce_kw<<<dim3((NSLOTS * (size_t)D_DIM) / 1024), blk, 0, stream>>>(
        kwpart, KW, kwb);

    // approx scores (bf16 out) = xb @ kwb^T  [overwrites kwpart region]
    gemm_bf16_abt<true><<<dim3(NSLOTS / 128, BT_DIM / 128), blk, 0, stream>>>(
        xb, kwb, scoresb, BT_DIM, NSLOTS, D_DIM);

    // per-tile top-4 summary (branchless packed-key argmax)
    aux_pass<<<dim3(BT_DIM / 4), blk, 0, stream>>>(scoresb, aux);

    // exact top-4 via aux + margin-refine; writes retrieved (bf16) over xb
    topk_refine<<<dim3(BT_DIM / 4), blk, 0, stream>>>(
        aux, scoresb, x, KW, svb, xb);

    // out = retrieved @ Wout^T  (fp32 out)
    gemm_bf16_abt<false><<<dim3(D_DIM / 128, BT_DIM / 128), blk, 0, stream>>>(
        xb, woutb, (float*)d_out, BT_DIM, D_DIM, D_DIM);
}

// Round 10
// 1312.748 us; speedup vs baseline: 1.0866x; 1.0866x over previous
//
#include <hip/hip_runtime.h>
#include <math.h>

#define D_DIM    2048
#define BT_DIM   16384   // B*T
#define NSLOTS   4096
#define NTILES   32      // NSLOTS / 128
#define SCALE    0.02209708691207961f  // 1/sqrt(2048)
#define MARGIN   0.02f
#define CAND_MAX 16
#define KSPLIT   4

typedef __attribute__((ext_vector_type(8))) short bf16x8;
typedef __attribute__((ext_vector_type(4))) float f32x4;
typedef __attribute__((ext_vector_type(8))) unsigned short u16x8;
typedef __attribute__((ext_vector_type(4))) unsigned short u16x4;

__device__ __forceinline__ unsigned short f2bf(float f) {
    unsigned int u = __float_as_uint(f);
    return (unsigned short)((u + 0x7fffu + ((u >> 16) & 1u)) >> 16);
}
__device__ __forceinline__ float bf2f(unsigned short s) {
    return __uint_as_float(((unsigned int)s) << 16);
}

__device__ __forceinline__ void async_cp16(const void* g, void* l) {
    __builtin_amdgcn_global_load_lds(
        (const __attribute__((address_space(1))) void*)g,
        (__attribute__((address_space(3))) void*)l, 16, 0, 0);
}

// ---------------------------------------------------------------------------
// top-4 helpers (jax semantics: val desc, idx asc) -- used in refine merge
// ---------------------------------------------------------------------------
__device__ __forceinline__ bool cand_better(float v, int i, float v2, int i2) {
    return (v > v2) || (v == v2 && i < i2);
}

__device__ __forceinline__ void cand_insert(float v, int idx,
                                            float& v0, int& i0, float& v1, int& i1,
                                            float& v2, int& i2, float& v3, int& i3) {
    if (cand_better(v, idx, v3, i3)) {
        if (cand_better(v, idx, v0, i0)) {
            v3 = v2; i3 = i2; v2 = v1; i2 = i1; v1 = v0; i1 = i0; v0 = v; i0 = idx;
        } else if (cand_better(v, idx, v1, i1)) {
            v3 = v2; i3 = i2; v2 = v1; i2 = i1; v1 = v; i1 = idx;
        } else if (cand_better(v, idx, v2, i2)) {
            v3 = v2; i3 = i2; v2 = v; i2 = idx;
        } else {
            v3 = v; i3 = idx;
        }
    }
}

// ---------------------------------------------------------------------------
// fp32: Cpart[z] = A[M,Kc] @ B[Kc,N] for K-chunk z -- EXACT r7 baseline.
// KNOWN-GOOD math (rounds 2-7): per-16-step local accumulator feeds the
// exact-refine path. r8/r9 lessons: pad/prefetch/BK=32/fused-cvt all
// neutral-to-negative here; this kernel is near its structure ceiling
// (~79 TF vs m07's 103 TF measured scalar-FMA ceiling). DO NOT TOUCH.
// ---------------------------------------------------------------------------
__global__ __launch_bounds__(256)
void gemm_ab_f32_ksplit(const float* __restrict__ A, const float* __restrict__ B,
                        float* __restrict__ Cpart, int M, int N, int K) {
    __shared__ float As[16][128];   // [k][m]
    __shared__ float Bs[16][128];   // [k][n]

    const int tid = threadIdx.x;
    const int bm  = blockIdx.y * 128;
    const int bn  = blockIdx.x * 128;
    const int kc  = K / KSPLIT;
    const int ks  = blockIdx.z * kc;
    float* C = Cpart + (size_t)blockIdx.z * M * N;
    const int ty  = tid >> 4;
    const int tx  = tid & 15;

    float acc[2][2][4][4];
#pragma unroll
    for (int rb = 0; rb < 2; ++rb)
#pragma unroll
        for (int cb = 0; cb < 2; ++cb)
#pragma unroll
            for (int i = 0; i < 4; ++i)
#pragma unroll
                for (int j = 0; j < 4; ++j) acc[rb][cb][i][j] = 0.0f;

    for (int k0 = ks; k0 < ks + kc; k0 += 16) {
#pragma unroll
        for (int half = 0; half < 2; ++half) {
            const int p = tid + half * 256;
            const int rowA = p >> 2;
            const int kkA  = (p & 3) << 2;
            float4 a4 = *(const float4*)(A + (size_t)(bm + rowA) * K + (k0 + kkA));
            As[kkA + 0][rowA] = a4.x;
            As[kkA + 1][rowA] = a4.y;
            As[kkA + 2][rowA] = a4.z;
            As[kkA + 3][rowA] = a4.w;
            const int kB = p >> 5;
            const int n4 = (p & 31) << 2;
            float4 b4 = *(const float4*)(B + (size_t)(k0 + kB) * N + (bn + n4));
            *(float4*)&Bs[kB][n4] = b4;
        }
        __syncthreads();

        float lacc[2][2][4][4];
#pragma unroll
        for (int rb = 0; rb < 2; ++rb)
#pragma unroll
            for (int cb = 0; cb < 2; ++cb)
#pragma unroll
                for (int i = 0; i < 4; ++i)
#pragma unroll
                    for (int j = 0; j < 4; ++j) lacc[rb][cb][i][j] = 0.0f;

#pragma unroll
        for (int k = 0; k < 16; ++k) {
            float a[2][4], b[2][4];
#pragma unroll
            for (int h = 0; h < 2; ++h) {
                *(float4*)a[h] = *(const float4*)&As[k][h * 64 + ty * 4];
                *(float4*)b[h] = *(const float4*)&Bs[k][h * 64 + tx * 4];
            }
#pragma unroll
            for (int rb = 0; rb < 2; ++rb)
#pragma unroll
                for (int cb = 0; cb < 2; ++cb)
#pragma unroll
                    for (int i = 0; i < 4; ++i)
#pragma unroll
                        for (int j = 0; j < 4; ++j)
                            lacc[rb][cb][i][j] =
                                fmaf(a[rb][i], b[cb][j], lacc[rb][cb][i][j]);
        }
#pragma unroll
        for (int rb = 0; rb < 2; ++rb)
#pragma unroll
            for (int cb = 0; cb < 2; ++cb)
#pragma unroll
                for (int i = 0; i < 4; ++i)
#pragma unroll
                    for (int j = 0; j < 4; ++j)
                        acc[rb][cb][i][j] += lacc[rb][cb][i][j];
        __syncthreads();
    }

#pragma unroll
    for (int rb = 0; rb < 2; ++rb)
#pragma unroll
        for (int i = 0; i < 4; ++i) {
            const size_t r = (size_t)(bm + rb * 64 + ty * 4 + i);
#pragma unroll
            for (int cb = 0; cb < 2; ++cb) {
                float4 o;
                o.x = acc[rb][cb][i][0];
                o.y = acc[rb][cb][i][1];
                o.z = acc[rb][cb][i][2];
                o.w = acc[rb][cb][i][3];
                *(float4*)(C + r * N + (bn + cb * 64 + tx * 4)) = o;
            }
        }
}

// ---------------------------------------------------------------------------
// KW = sum of 4 K-chunk partials (deterministic); also emit kwb = bf16(KW).
// ---------------------------------------------------------------------------
__global__ __launch_bounds__(256)
void reduce_kw(const float* __restrict__ part, float* __restrict__ KW,
               unsigned short* __restrict__ kwb) {
    const size_t i = ((size_t)blockIdx.x * 256 + threadIdx.x) * 4;
    const size_t stride = (size_t)NSLOTS * D_DIM;
    float4 s0 = *(const float4*)(part + i);
    float4 s1 = *(const float4*)(part + i + stride);
    float4 s2 = *(const float4*)(part + i + 2 * stride);
    float4 s3 = *(const float4*)(part + i + 3 * stride);
    float4 o;
    o.x = (s0.x + s1.x) + (s2.x + s3.x);
    o.y = (s0.y + s1.y) + (s2.y + s3.y);
    o.z = (s0.z + s1.z) + (s2.z + s3.z);
    o.w = (s0.w + s1.w) + (s2.w + s3.w);
    *(float4*)(KW + i) = o;
    u16x4 b;
    b[0] = f2bf(o.x); b[1] = f2bf(o.y); b[2] = f2bf(o.z); b[3] = f2bf(o.w);
    *(u16x4*)(kwb + i) = b;
}

// ---------------------------------------------------------------------------
// fp32 -> bf16 elementwise (8 elems/thread), exact grid
// ---------------------------------------------------------------------------
__global__ __launch_bounds__(256)
void cvt_f32_bf16(const float* __restrict__ in, unsigned short* __restrict__ out) {
    const size_t i = ((size_t)blockIdx.x * 256 + threadIdx.x) * 8;
    float4 a = *(const float4*)(in + i);
    float4 b = *(const float4*)(in + i + 4);
    u16x8 o;
    o[0] = f2bf(a.x); o[1] = f2bf(a.y); o[2] = f2bf(a.z); o[3] = f2bf(a.w);
    o[4] = f2bf(b.x); o[5] = f2bf(b.y); o[6] = f2bf(b.z); o[7] = f2bf(b.w);
    *(u16x8*)(out + i) = o;
}

// ---------------------------------------------------------------------------
// bf16 MFMA GEMM (out-projection): C[M,N] = A[M,K] @ B[N,K]^T, fp32 out.
// m97 structure, PURE, NO swizzle (r8: swizzle -45us on L3-resident data).
// ---------------------------------------------------------------------------
__global__ __launch_bounds__(256)
void gemm_bf16_abt(const unsigned short* __restrict__ A,
                   const unsigned short* __restrict__ B,
                   float* __restrict__ C, int M, int N, int K) {
    __shared__ __align__(16) unsigned short Alds[128 * 32];
    __shared__ __align__(16) unsigned short Blds[128 * 32];

    const int tid  = threadIdx.x;
    const int lane = tid & 63;
    const int w    = tid >> 6;
    const int wr   = w >> 1, wc = w & 1;
    const int bm   = blockIdx.y * 128;
    const int bn   = blockIdx.x * 128;

    const int srow = lane >> 2;
    const int skch = (lane & 3) ^ ((lane >> 3) & 3);
    const int c0 = w, c1 = w + 4;
    const unsigned short* gA0 = A + (size_t)(bm + c0 * 16 + srow) * K + skch * 8;
    const unsigned short* gA1 = A + (size_t)(bm + c1 * 16 + srow) * K + skch * 8;
    const unsigned short* gB0 = B + (size_t)(bn + c0 * 16 + srow) * K + skch * 8;
    const unsigned short* gB1 = B + (size_t)(bn + c1 * 16 + srow) * K + skch * 8;
    char* lA0 = (char*)Alds + c0 * 1024;
    char* lA1 = (char*)Alds + c1 * 1024;
    char* lB0 = (char*)Blds + c0 * 1024;
    char* lB1 = (char*)Blds + c1 * 1024;

    const int kbyte = (((lane >> 4) ^ ((lane >> 1) & 3)) << 4);
    const int rA = wr * 64 + (lane & 15);
    const int rB = wc * 64 + (lane & 15);

    f32x4 acc[4][4] = {};

    for (int kt = 0; kt < K; kt += 32) {
        async_cp16(gA0, lA0);
        async_cp16(gA1, lA1);
        async_cp16(gB0, lB0);
        async_cp16(gB1, lB1);
        gA0 += 32; gA1 += 32; gB0 += 32; gB1 += 32;
        __syncthreads();

        bf16x8 a[4], b[4];
#pragma unroll
        for (int i = 0; i < 4; ++i) {
            a[i] = *(const bf16x8*)((const char*)Alds + (rA + i * 16) * 64 + kbyte);
            b[i] = *(const bf16x8*)((const char*)Blds + (rB + i * 16) * 64 + kbyte);
        }
#pragma unroll
        for (int i = 0; i < 4; ++i)
#pragma unroll
            for (int j = 0; j < 4; ++j)
                acc[i][j] = __builtin_amdgcn_mfma_f32_16x16x32_bf16(
                    a[i], b[j], acc[i][j], 0, 0, 0);
        __syncthreads();
    }

    const int orow = (lane >> 4) * 4;
    const int ocol = lane & 15;
#pragma unroll
    for (int i = 0; i < 4; ++i)
#pragma unroll
        for (int j = 0; j < 4; ++j) {
            const size_t base =
                (size_t)(bm + wr * 64 + i * 16 + orow) * N + (bn + wc * 64 + j * 16 + ocol);
#pragma unroll
            for (int r = 0; r < 4; ++r)
                C[base + (size_t)r * N] = acc[i][j][r];
        }
}

// ---------------------------------------------------------------------------
// Scores GEMM + fused BRANCHLESS per-tile top-4 epilogue.
// Main loop identical to gemm_bf16_abt. Epilogue = r7's validated packed-key
// argmax (NOT r5's branchy insertion sort that spilled): per (i,r) row slice,
// 4 passes of {max-tree -> 16-lane shfl-max -> mask}; cross-wave merge of
// 8 keys/row via LDS (reusing Alds). Writes scoresb (fallback) + aux.
// Keys are built from f2bf(acc) == stored scoresb values -> aux is
// bit-identical to what r7's separate aux_pass produced.
// ---------------------------------------------------------------------------
__global__ __launch_bounds__(256)
void gemm_scores_fused(const unsigned short* __restrict__ A,
                       const unsigned short* __restrict__ B,
                       unsigned short* __restrict__ Cb,
                       float4* __restrict__ aux, int M, int N, int K) {
    __shared__ __align__(16) unsigned short Alds[128 * 32];
    __shared__ __align__(16) unsigned short Blds[128 * 32];

    const int tid  = threadIdx.x;
    const int lane = tid & 63;
    const int w    = tid >> 6;
    const int wr   = w >> 1, wc = w & 1;
    const int bm   = blockIdx.y * 128;
    const int bn   = blockIdx.x * 128;

    const int srow = lane >> 2;
    const int skch = (lane & 3) ^ ((lane >> 3) & 3);
    const int c0 = w, c1 = w + 4;
    const unsigned short* gA0 = A + (size_t)(bm + c0 * 16 + srow) * K + skch * 8;
    const unsigned short* gA1 = A + (size_t)(bm + c1 * 16 + srow) * K + skch * 8;
    const unsigned short* gB0 = B + (size_t)(bn + c0 * 16 + srow) * K + skch * 8;
    const unsigned short* gB1 = B + (size_t)(bn + c1 * 16 + srow) * K + skch * 8;
    char* lA0 = (char*)Alds + c0 * 1024;
    char* lA1 = (char*)Alds + c1 * 1024;
    char* lB0 = (char*)Blds + c0 * 1024;
    char* lB1 = (char*)Blds + c1 * 1024;

    const int kbyte = (((lane >> 4) ^ ((lane >> 1) & 3)) << 4);
    const int rA = wr * 64 + (lane & 15);
    const int rB = wc * 64 + (lane & 15);

    f32x4 acc[4][4] = {};

    for (int kt = 0; kt < K; kt += 32) {
        async_cp16(gA0, lA0);
        async_cp16(gA1, lA1);
        async_cp16(gB0, lB0);
        async_cp16(gB1, lB1);
        gA0 += 32; gA1 += 32; gB0 += 32; gB1 += 32;
        __syncthreads();

        bf16x8 a[4], b[4];
#pragma unroll
        for (int i = 0; i < 4; ++i) {
            a[i] = *(const bf16x8*)((const char*)Alds + (rA + i * 16) * 64 + kbyte);
            b[i] = *(const bf16x8*)((const char*)Blds + (rB + i * 16) * 64 + kbyte);
        }
#pragma unroll
        for (int i = 0; i < 4; ++i)
#pragma unroll
            for (int j = 0; j < 4; ++j)
                acc[i][j] = __builtin_amdgcn_mfma_f32_16x16x32_bf16(
                    a[i], b[j], acc[i][j], 0, 0, 0);
        __syncthreads();
    }

    // ---- store bf16 scores (fallback data for flagged-tile rescan)
    const int g    = lane >> 4;        // 0..3 (row group)
    const int lcol = lane & 15;        // 0..15
#pragma unroll
    for (int i = 0; i < 4; ++i)
#pragma unroll
        for (int j = 0; j < 4; ++j) {
            const size_t base =
                (size_t)(bm + wr * 64 + i * 16 + g * 4) * N + (bn + wc * 64 + j * 16 + lcol);
#pragma unroll
            for (int r = 0; r < 4; ++r)
                Cb[base + (size_t)r * N] = f2bf(acc[i][j][r]);
        }

    // ---- branchless per-row top-4 over this block's 128 cols (= 1 tile)
    unsigned int* mrg = (unsigned int*)Alds;   // [128 rows][8 keys], 4 KB
#pragma unroll
    for (int i = 0; i < 4; ++i) {
#pragma unroll
        for (int r = 0; r < 4; ++r) {
            unsigned int k[4];
#pragma unroll
            for (int j = 0; j < 4; ++j) {
                const unsigned int b   = (unsigned int)f2bf(acc[i][j][r]) & 0xffffu;
                const unsigned int ord = b ^ ((b & 0x8000u) ? 0xffffu : 0x8000u);
                const unsigned int gcol = (unsigned int)(bn + wc * 64 + j * 16 + lcol);
                k[j] = (ord << 12) | (4095u - gcol);
            }
            unsigned int win[4];
#pragma unroll
            for (int p = 0; p < 4; ++p) {
                unsigned int m = max(max(k[0], k[1]), max(k[2], k[3]));
#pragma unroll
                for (int off = 1; off < 16; off <<= 1)
                    m = max(m, (unsigned int)__shfl_xor((int)m, off));
                win[p] = m;
#pragma unroll
                for (int j = 0; j < 4; ++j) k[j] = (k[j] == m) ? 0u : k[j];
            }
            if (lcol == 0) {
                const int row = wr * 64 + i * 16 + g * 4 + r;   // 0..127
                uint4 wv;
                wv.x = win[0]; wv.y = win[1]; wv.z = win[2]; wv.w = win[3];
                *(uint4*)&mrg[row * 8 + wc * 4] = wv;
            }
        }
    }
    __syncthreads();

    // ---- merge the two 64-col halves (8 keys/row), write aux
    if (tid < 128) {
        uint4 h0 = *(const uint4*)&mrg[tid * 8];
        uint4 h1 = *(const uint4*)&mrg[tid * 8 + 4];
        unsigned int kk[8] = {h0.x, h0.y, h0.z, h0.w, h1.x, h1.y, h1.z, h1.w};
        float vv[4]; int id[4];
#pragma unroll
        for (int p = 0; p < 4; ++p) {
            unsigned int m01 = max(kk[0], kk[1]), m23 = max(kk[2], kk[3]);
            unsigned int m45 = max(kk[4], kk[5]), m67 = max(kk[6], kk[7]);
            unsigned int m = max(max(m01, m23), max(m45, m67));
#pragma unroll
            for (int e = 0; e < 8; ++e) kk[e] = (kk[e] == m) ? 0u : kk[e];
            const unsigned int ord = m >> 12;
            const unsigned int b =
                (ord & 0x8000u) ? (ord ^ 0x8000u) : (~ord & 0xffffu);
            vv[p] = bf2f((unsigned short)b);
            id[p] = 4095 - (int)(m & 0xfffu);
        }
        float4 o1, o2;
        o1.x = vv[0]; o1.y = __int_as_float(id[0]);
        o1.z = vv[1]; o1.w = __int_as_float(id[1]);
        o2.x = vv[2]; o2.y = __int_as_float(id[2]);
        o2.z = vv[3]; o2.w = __int_as_float(id[3]);
        float4* dst = aux + ((size_t)(bm + tid) * NTILES + blockIdx.x) * 2;
        dst[0] = o1;
        dst[1] = o2;
    }
}

// ---------------------------------------------------------------------------
// Wave-per-row refine: merge aux -> thresh -> candidates (aux + rare flagged
// tile rescan) -> EXACT fp32 re-score (identical math, rounds 2-9) ->
// softmax -> gather.  UNCHANGED from r7.
// ---------------------------------------------------------------------------
__global__ __launch_bounds__(256)
void topk_refine(const float4* __restrict__ aux,
                 const unsigned short* __restrict__ scoresb,
                 const float* __restrict__ x,
                 const float* __restrict__ KW,
                 const unsigned short* __restrict__ svb,
                 unsigned short* __restrict__ retr) {
    const int tid  = threadIdx.x;
    const int lane = tid & 63;
    const int w    = tid >> 6;
    const int t    = blockIdx.x * 4 + w;

    const float* xrow = x + (size_t)t * D_DIM + lane * 4;
    float4 xv[8];
#pragma unroll
    for (int i = 0; i < 8; ++i) xv[i] = *(const float4*)(xrow + 256 * i);

    __shared__ int          cand[4][CAND_MAX];
    __shared__ int          ncand[4];
    __shared__ unsigned int flags[4];
    if (lane == 0) { ncand[w] = 0; flags[w] = 0; }
    __syncthreads();

    const float4 e2 = aux[(size_t)t * 64 + lane];
    float v0 = -INFINITY, v1 = -INFINITY, v2 = -INFINITY, v3 = -INFINITY;
    int   i0 = 0x7fffffff, i1 = 0x7fffffff, i2 = 0x7fffffff, i3 = 0x7fffffff;
    cand_insert(e2.x, __float_as_int(e2.y), v0, i0, v1, i1, v2, i2, v3, i3);
    cand_insert(e2.z, __float_as_int(e2.w), v0, i0, v1, i1, v2, i2, v3, i3);
#pragma unroll
    for (int off = 1; off < 64; off <<= 1) {
        float s0 = __shfl_xor(v0, off), s1 = __shfl_xor(v1, off);
        float s2 = __shfl_xor(v2, off), s3 = __shfl_xor(v3, off);
        int   j0 = __shfl_xor(i0, off), j1 = __shfl_xor(i1, off);
        int   j2 = __shfl_xor(i2, off), j3 = __shfl_xor(i3, off);
        cand_insert(s0, j0, v0, i0, v1, i1, v2, i2, v3, i3);
        cand_insert(s1, j1, v0, i0, v1, i1, v2, i2, v3, i3);
        cand_insert(s2, j2, v0, i0, v1, i1, v2, i2, v3, i3);
        cand_insert(s3, j3, v0, i0, v1, i1, v2, i2, v3, i3);
    }
    const float thresh = v3 - MARGIN;

    if ((lane & 1) && e2.z >= thresh)
        atomicOr(&flags[w], 1u << (lane >> 1));
    __syncthreads();
    const unsigned int fl = flags[w];

    const int mytile = lane >> 1;
    if (!((fl >> mytile) & 1u)) {
        if (e2.x >= thresh) {
            int p = atomicAdd(&ncand[w], 1);
            if (p < CAND_MAX) cand[w][p] = __float_as_int(e2.y);
        }
        if (e2.z >= thresh) {
            int p = atomicAdd(&ncand[w], 1);
            if (p < CAND_MAX) cand[w][p] = __float_as_int(e2.w);
        }
    }
    unsigned int fscan = fl;
    while (fscan) {
        const int tb = __ffs(fscan) - 1;
        fscan &= fscan - 1;
        const unsigned short* srow =
            scoresb + (size_t)t * NSLOTS + tb * 128 + lane * 2;
        const unsigned short s0 = srow[0], s1 = srow[1];
        if (bf2f(s0) >= thresh) {
            int p = atomicAdd(&ncand[w], 1);
            if (p < CAND_MAX) cand[w][p] = tb * 128 + lane * 2;
        }
        if (bf2f(s1) >= thresh) {
            int p = atomicAdd(&ncand[w], 1);
            if (p < CAND_MAX) cand[w][p] = tb * 128 + lane * 2 + 1;
        }
    }
    __syncthreads();
    const int nc = min(ncand[w], CAND_MAX);

    float r0 = -INFINITY, r1 = -INFINITY, r2 = -INFINITY, r3 = -INFINITY;
    int   q0 = 0x7fffffff, q1 = 0x7fffffff, q2 = 0x7fffffff, q3 = 0x7fffffff;
    for (int c = 0; c < nc; ++c) {
        const int slot = cand[w][c];
        const float* kr = KW + (size_t)slot * D_DIM + lane * 4;
        float p = 0.0f;
#pragma unroll
        for (int i = 0; i < 8; ++i) {
            const float4 k4 = *(const float4*)(kr + 256 * i);
            p = fmaf(xv[i].x, k4.x, p);
            p = fmaf(xv[i].y, k4.y, p);
            p = fmaf(xv[i].z, k4.z, p);
            p = fmaf(xv[i].w, k4.w, p);
        }
#pragma unroll
        for (int off = 1; off < 64; off <<= 1) p += __shfl_xor(p, off);
        cand_insert(p, slot, r0, q0, r1, q1, r2, q2, r3, q3);
    }

    const float e1s = expf(SCALE * (r1 - r0));
    const float e2s = expf(SCALE * (r2 - r0));
    const float e3s = expf(SCALE * (r3 - r0));
    const float inv = 1.0f / (1.0f + e1s + e2s + e3s);
    const float w0s = inv, w1s = e1s * inv, w2s = e2s * inv, w3s = e3s * inv;

    const unsigned short* p0 = svb + (size_t)q0 * D_DIM;
    const unsigned short* p1 = svb + (size_t)q1 * D_DIM;
    const unsigned short* p2 = svb + (size_t)q2 * D_DIM;
    const unsigned short* p3 = svb + (size_t)q3 * D_DIM;
    unsigned short* orow = retr + (size_t)t * D_DIM;
#pragma unroll
    for (int i = 0; i < 4; ++i) {
        const int d0 = lane * 8 + 512 * i;
        u16x8 a0 = *(const u16x8*)(p0 + d0);
        u16x8 a1 = *(const u16x8*)(p1 + d0);
        u16x8 a2 = *(const u16x8*)(p2 + d0);
        u16x8 a3 = *(const u16x8*)(p3 + d0);
        u16x8 o;
#pragma unroll
        for (int e = 0; e < 8; ++e) {
            float s = w0s * bf2f(a0[e]) + w1s * bf2f(a1[e]) +
                      w2s * bf2f(a2[e]) + w3s * bf2f(a3[e]);
            o[e] = f2bf(s);
        }
        *(u16x8*)(orow + d0) = o;
    }
}

// ---------------------------------------------------------------------------
extern "C" void kernel_launch(void* const* d_in, const int* in_sizes, int n_in,
                              void* d_out, int out_size, void* d_ws, size_t ws_size,
                              hipStream_t stream) {
    const float* x    = (const float*)d_in[0];
    const float* sk   = (const float*)d_in[1];
    const float* sv   = (const float*)d_in[2];
    const float* wq   = (const float*)d_in[3];
    const float* wout = (const float*)d_in[4];

    // workspace layout (293.6 MB; proven ws >= 402 MB)
    char* base = (char*)d_ws;
    float*          kwpart  = (float*)base;                       // 4 x 33.55 MB (then reused)
    unsigned short* scoresb = (unsigned short*)base;              // 134.2 MB (after reduce)
    float*          KW      = (float*)(base + 134217728);         //  33.55 MB
    unsigned short* kwb     = (unsigned short*)(base + 167772160);//  16.78 MB
    unsigned short* woutb   = (unsigned short*)(base + 184549376);//   8.39 MB
    unsigned short* xb      = (unsigned short*)(base + 192937984);//  67.11 MB (reused as retr)
    unsigned short* svb     = (unsigned short*)(base + 260046848);//  16.78 MB
    float4*         aux     = (float4*)(base + 276824064);        //  16.78 MB

    const dim3 blk(256);

    // KW partials: SK @ Wq, K split 4 ways (r7 exact baseline)
    gemm_ab_f32_ksplit<<<dim3(D_DIM / 128, NSLOTS / 128, KSPLIT), blk, 0, stream>>>(
        sk, wq, kwpart, NSLOTS, D_DIM, D_DIM);

    // KW = sum(partials); kwb = bf16(KW)
    reduce_kw<<<dim3((NSLOTS * (size_t)D_DIM) / 1024), blk, 0, stream>>>(
        kwpart, KW, kwb);

    // bf16 copies
    cvt_f32_bf16<<<dim3((BT_DIM * (size_t)D_DIM) / 2048), blk, 0, stream>>>(x, xb);
    cvt_f32_bf16<<<dim3((D_DIM * (size_t)D_DIM) / 2048), blk, 0, stream>>>(wout, woutb);
    cvt_f32_bf16<<<dim3((NSLOTS * (size_t)D_DIM) / 2048), blk, 0, stream>>>(sv, svb);

    // approx scores (bf16) + fused branchless per-tile top-4 aux
    gemm_scores_fused<<<dim3(NSLOTS / 128, BT_DIM / 128), blk, 0, stream>>>(
        xb, kwb, scoresb, aux, BT_DIM, NSLOTS, D_DIM);

    // exact top-4 via aux + margin-refine; writes retrieved (bf16) over xb
    topk_refine<<<dim3(BT_DIM / 4), blk, 0, stream>>>(
        aux, scoresb, x, KW, svb, xb);

    // out = retrieved @ Wout^T  (fp32 out)
    gemm_bf16_abt<<<dim3(D_DIM / 128, BT_DIM / 128), blk, 0, stream>>>(
        xb, woutb, (float*)d_out, BT_DIM, D_DIM, D_DIM);
}

// Round 12
// 1066.121 us; speedup vs baseline: 1.3380x; 1.2313x over previous
//
#include <hip/hip_runtime.h>
#include <math.h>

#define D_DIM    2048
#define BT_DIM   16384   // B*T
#define NSLOTS   4096
#define NTILES   32      // NSLOTS / 128
#define SCALE    0.02209708691207961f  // 1/sqrt(2048)
#define MARGIN   0.02f
#define CAND_MAX 16

typedef __attribute__((ext_vector_type(8))) short bf16x8;
typedef __attribute__((ext_vector_type(4))) float f32x4;
typedef __attribute__((ext_vector_type(8))) unsigned short u16x8;
typedef __attribute__((ext_vector_type(4))) unsigned short u16x4;

__device__ __forceinline__ unsigned short f2bf(float f) {
    unsigned int u = __float_as_uint(f);
    return (unsigned short)((u + 0x7fffu + ((u >> 16) & 1u)) >> 16);
}
__device__ __forceinline__ float bf2f(unsigned short s) {
    return __uint_as_float(((unsigned int)s) << 16);
}

__device__ __forceinline__ void async_cp16(const void* g, void* l) {
    __builtin_amdgcn_global_load_lds(
        (const __attribute__((address_space(1))) void*)g,
        (__attribute__((address_space(3))) void*)l, 16, 0, 0);
}

// ---------------------------------------------------------------------------
// top-4 helpers (jax semantics: val desc, idx asc) -- used in refine merge
// ---------------------------------------------------------------------------
__device__ __forceinline__ bool cand_better(float v, int i, float v2, int i2) {
    return (v > v2) || (v == v2 && i < i2);
}

__device__ __forceinline__ void cand_insert(float v, int idx,
                                            float& v0, int& i0, float& v1, int& i1,
                                            float& v2, int& i2, float& v3, int& i3) {
    if (cand_better(v, idx, v3, i3)) {
        if (cand_better(v, idx, v0, i0)) {
            v3 = v2; i3 = i2; v2 = v1; i2 = i1; v1 = v0; i1 = i0; v0 = v; i0 = idx;
        } else if (cand_better(v, idx, v1, i1)) {
            v3 = v2; i3 = i2; v2 = v1; i2 = i1; v1 = v; i1 = idx;
        } else if (cand_better(v, idx, v2, i2)) {
            v3 = v2; i3 = i2; v2 = v; i2 = idx;
        } else {
            v3 = v; i3 = idx;
        }
    }
}

// ---------------------------------------------------------------------------
// 3-way bf16 split: v = h + m + l (each bf16, residual ~2^-27 |v|)
// (r11 compile fix: plain scalar refs only -- ext_vector elements can't bind
// to non-const references; callers use locals.)
// ---------------------------------------------------------------------------
__device__ __forceinline__ void split3v(float v, unsigned short& h,
                                        unsigned short& m, unsigned short& l) {
    h = f2bf(v);
    const float r1 = v - bf2f(h);
    m = f2bf(r1);
    l = f2bf(r1 - bf2f(m));
}

// SK -> 3 bf16 component arrays (linear, 4 elems/thread)
__global__ __launch_bounds__(256)
void split3_lin(const float* __restrict__ in, unsigned short* __restrict__ oh,
                unsigned short* __restrict__ om, unsigned short* __restrict__ ol) {
    const size_t i = ((size_t)blockIdx.x * 256 + threadIdx.x) * 4;
    const float4 v = *(const float4*)(in + i);
    u16x4 h, m, l;
    unsigned short th, tm, tl;
    split3v(v.x, th, tm, tl); h[0] = th; m[0] = tm; l[0] = tl;
    split3v(v.y, th, tm, tl); h[1] = th; m[1] = tm; l[1] = tl;
    split3v(v.z, th, tm, tl); h[2] = th; m[2] = tm; l[2] = tl;
    split3v(v.w, th, tm, tl); h[3] = th; m[3] = tm; l[3] = tl;
    *(u16x4*)(oh + i) = h;
    *(u16x4*)(om + i) = m;
    *(u16x4*)(ol + i) = l;
}

// Wq[e][d] -> transposed 3 bf16 component arrays out[d][e]  (32x32 LDS tiles)
__global__ __launch_bounds__(256)
void split3_wqT(const float* __restrict__ W, unsigned short* __restrict__ th,
                unsigned short* __restrict__ tm, unsigned short* __restrict__ tl) {
    __shared__ float tile[32][33];
    const int tx  = threadIdx.x & 31;
    const int ty4 = (threadIdx.x >> 5) * 4;
    const int e0  = blockIdx.y * 32;
    const int d0  = blockIdx.x * 32;
#pragma unroll
    for (int r = 0; r < 4; ++r)
        tile[ty4 + r][tx] = W[(size_t)(e0 + ty4 + r) * D_DIM + (d0 + tx)];
    __syncthreads();
#pragma unroll
    for (int r = 0; r < 4; ++r) {
        const float v = tile[tx][ty4 + r];   // = W[e0+tx][d0+ty4+r]
        unsigned short h, m, l;
        split3v(v, h, m, l);
        const size_t o = (size_t)(d0 + ty4 + r) * D_DIM + (e0 + tx);
        th[o] = h; tm[o] = m; tl[o] = l;
    }
}

// ---------------------------------------------------------------------------
// fp32 -> bf16 elementwise (8 elems/thread), exact grid
// ---------------------------------------------------------------------------
__global__ __launch_bounds__(256)
void cvt_f32_bf16(const float* __restrict__ in, unsigned short* __restrict__ out) {
    const size_t i = ((size_t)blockIdx.x * 256 + threadIdx.x) * 8;
    float4 a = *(const float4*)(in + i);
    float4 b = *(const float4*)(in + i + 4);
    u16x8 o;
    o[0] = f2bf(a.x); o[1] = f2bf(a.y); o[2] = f2bf(a.z); o[3] = f2bf(a.w);
    o[4] = f2bf(b.x); o[5] = f2bf(b.y); o[6] = f2bf(b.z); o[7] = f2bf(b.w);
    *(u16x8*)(out + i) = o;
}

// ---------------------------------------------------------------------------
// KW = SK @ Wq via 6-product split-bf16 MFMA (fp32-grade):
//   C = Ah*Bh + Ah*Bm + Am*Bh + Am*Bm + Ah*Bl + Al*Bh
// (dropped ml/lm/ll terms ~2^-27 rel; accumulation fp32 in MFMA).
// m97 staging structure x3 components; epilogue writes KW fp32 + kwb bf16.
// Replaces gemm_ab_f32_ksplit (437us VALU-bound) + reduce_kw.
// ---------------------------------------------------------------------------
__global__ __launch_bounds__(256)
void gemm_kw_mfma6(const unsigned short* __restrict__ Ah,
                   const unsigned short* __restrict__ Am,
                   const unsigned short* __restrict__ Al,
                   const unsigned short* __restrict__ Bh,
                   const unsigned short* __restrict__ Bm,
                   const unsigned short* __restrict__ Bl,
                   float* __restrict__ KW, unsigned short* __restrict__ kwb,
                   int M, int N, int K) {
    __shared__ __align__(16) unsigned short AldsH[128 * 32];
    __shared__ __align__(16) unsigned short AldsM[128 * 32];
    __shared__ __align__(16) unsigned short AldsL[128 * 32];
    __shared__ __align__(16) unsigned short BldsH[128 * 32];
    __shared__ __align__(16) unsigned short BldsM[128 * 32];
    __shared__ __align__(16) unsigned short BldsL[128 * 32];

    const int tid  = threadIdx.x;
    const int lane = tid & 63;
    const int w    = tid >> 6;
    const int wr   = w >> 1, wc = w & 1;
    const int bmr  = blockIdx.y * 128;
    const int bnc  = blockIdx.x * 128;

    const int srow = lane >> 2;
    const int skch = (lane & 3) ^ ((lane >> 3) & 3);
    const int c0 = w, c1 = w + 4;
    size_t oA0 = (size_t)(bmr + c0 * 16 + srow) * K + skch * 8;
    size_t oA1 = (size_t)(bmr + c1 * 16 + srow) * K + skch * 8;
    size_t oB0 = (size_t)(bnc + c0 * 16 + srow) * K + skch * 8;
    size_t oB1 = (size_t)(bnc + c1 * 16 + srow) * K + skch * 8;
    char* lAh0 = (char*)AldsH + c0 * 1024;  char* lAh1 = (char*)AldsH + c1 * 1024;
    char* lAm0 = (char*)AldsM + c0 * 1024;  char* lAm1 = (char*)AldsM + c1 * 1024;
    char* lAl0 = (char*)AldsL + c0 * 1024;  char* lAl1 = (char*)AldsL + c1 * 1024;
    char* lBh0 = (char*)BldsH + c0 * 1024;  char* lBh1 = (char*)BldsH + c1 * 1024;
    char* lBm0 = (char*)BldsM + c0 * 1024;  char* lBm1 = (char*)BldsM + c1 * 1024;
    char* lBl0 = (char*)BldsL + c0 * 1024;  char* lBl1 = (char*)BldsL + c1 * 1024;

    const int kbyte = (((lane >> 4) ^ ((lane >> 1) & 3)) << 4);
    const int rA = wr * 64 + (lane & 15);
    const int rB = wc * 64 + (lane & 15);

    f32x4 acc[4][4] = {};

    for (int kt = 0; kt < K; kt += 32) {
        async_cp16(Ah + oA0, lAh0);  async_cp16(Ah + oA1, lAh1);
        async_cp16(Am + oA0, lAm0);  async_cp16(Am + oA1, lAm1);
        async_cp16(Al + oA0, lAl0);  async_cp16(Al + oA1, lAl1);
        async_cp16(Bh + oB0, lBh0);  async_cp16(Bh + oB1, lBh1);
        async_cp16(Bm + oB0, lBm0);  async_cp16(Bm + oB1, lBm1);
        async_cp16(Bl + oB0, lBl0);  async_cp16(Bl + oB1, lBl1);
        oA0 += 32; oA1 += 32; oB0 += 32; oB1 += 32;
        __syncthreads();

        bf16x8 afh[4], afm[4], afl[4], bfh[4], bfm[4], bfl[4];
#pragma unroll
        for (int i = 0; i < 4; ++i) {
            const int ar = (rA + i * 16) * 64 + kbyte;
            afh[i] = *(const bf16x8*)((const char*)AldsH + ar);
            afm[i] = *(const bf16x8*)((const char*)AldsM + ar);
            afl[i] = *(const bf16x8*)((const char*)AldsL + ar);
            const int br = (rB + i * 16) * 64 + kbyte;
            bfh[i] = *(const bf16x8*)((const char*)BldsH + br);
            bfm[i] = *(const bf16x8*)((const char*)BldsM + br);
            bfl[i] = *(const bf16x8*)((const char*)BldsL + br);
        }
#pragma unroll
        for (int i = 0; i < 4; ++i)
#pragma unroll
            for (int j = 0; j < 4; ++j) {
                f32x4 c = acc[i][j];
                c = __builtin_amdgcn_mfma_f32_16x16x32_bf16(afh[i], bfh[j], c, 0, 0, 0);
                c = __builtin_amdgcn_mfma_f32_16x16x32_bf16(afh[i], bfm[j], c, 0, 0, 0);
                c = __builtin_amdgcn_mfma_f32_16x16x32_bf16(afm[i], bfh[j], c, 0, 0, 0);
                c = __builtin_amdgcn_mfma_f32_16x16x32_bf16(afm[i], bfm[j], c, 0, 0, 0);
                c = __builtin_amdgcn_mfma_f32_16x16x32_bf16(afh[i], bfl[j], c, 0, 0, 0);
                c = __builtin_amdgcn_mfma_f32_16x16x32_bf16(afl[i], bfh[j], c, 0, 0, 0);
                acc[i][j] = c;
            }
        __syncthreads();
    }

    const int orow = (lane >> 4) * 4;
    const int ocol = lane & 15;
#pragma unroll
    for (int i = 0; i < 4; ++i)
#pragma unroll
        for (int j = 0; j < 4; ++j) {
            const size_t base =
                (size_t)(bmr + wr * 64 + i * 16 + orow) * N + (bnc + wc * 64 + j * 16 + ocol);
#pragma unroll
            for (int r = 0; r < 4; ++r) {
                const float v = acc[i][j][r];
                KW[base + (size_t)r * N]  = v;
                kwb[base + (size_t)r * N] = f2bf(v);
            }
        }
}

// ---------------------------------------------------------------------------
// bf16 MFMA GEMM: C[M,N] = A[M,K] @ B[N,K]^T; C fp32 or bf16 (template).
// r7 exact baseline (no swizzle, no epilogue fusion -- r8/r10 lessons).
// ---------------------------------------------------------------------------
template <bool BF16_OUT>
__global__ __launch_bounds__(256)
void gemm_bf16_abt(const unsigned short* __restrict__ A,
                   const unsigned short* __restrict__ B,
                   void* __restrict__ Cv, int M, int N, int K) {
    __shared__ __align__(16) unsigned short Alds[128 * 32];
    __shared__ __align__(16) unsigned short Blds[128 * 32];

    const int tid  = threadIdx.x;
    const int lane = tid & 63;
    const int w    = tid >> 6;
    const int wr   = w >> 1, wc = w & 1;
    const int bm   = blockIdx.y * 128;
    const int bn   = blockIdx.x * 128;

    const int srow = lane >> 2;
    const int skch = (lane & 3) ^ ((lane >> 3) & 3);
    const int c0 = w, c1 = w + 4;
    const unsigned short* gA0 = A + (size_t)(bm + c0 * 16 + srow) * K + skch * 8;
    const unsigned short* gA1 = A + (size_t)(bm + c1 * 16 + srow) * K + skch * 8;
    const unsigned short* gB0 = B + (size_t)(bn + c0 * 16 + srow) * K + skch * 8;
    const unsigned short* gB1 = B + (size_t)(bn + c1 * 16 + srow) * K + skch * 8;
    char* lA0 = (char*)Alds + c0 * 1024;
    char* lA1 = (char*)Alds + c1 * 1024;
    char* lB0 = (char*)Blds + c0 * 1024;
    char* lB1 = (char*)Blds + c1 * 1024;

    const int kbyte = (((lane >> 4) ^ ((lane >> 1) & 3)) << 4);
    const int rA = wr * 64 + (lane & 15);
    const int rB = wc * 64 + (lane & 15);

    f32x4 acc[4][4] = {};

    for (int kt = 0; kt < K; kt += 32) {
        async_cp16(gA0, lA0);
        async_cp16(gA1, lA1);
        async_cp16(gB0, lB0);
        async_cp16(gB1, lB1);
        gA0 += 32; gA1 += 32; gB0 += 32; gB1 += 32;
        __syncthreads();

        bf16x8 a[4], b[4];
#pragma unroll
        for (int i = 0; i < 4; ++i) {
            a[i] = *(const bf16x8*)((const char*)Alds + (rA + i * 16) * 64 + kbyte);
            b[i] = *(const bf16x8*)((const char*)Blds + (rB + i * 16) * 64 + kbyte);
        }
#pragma unroll
        for (int i = 0; i < 4; ++i)
#pragma unroll
            for (int j = 0; j < 4; ++j)
                acc[i][j] = __builtin_amdgcn_mfma_f32_16x16x32_bf16(
                    a[i], b[j], acc[i][j], 0, 0, 0);
        __syncthreads();
    }

    const int orow = (lane >> 4) * 4;
    const int ocol = lane & 15;
#pragma unroll
    for (int i = 0; i < 4; ++i)
#pragma unroll
        for (int j = 0; j < 4; ++j) {
            const size_t base =
                (size_t)(bm + wr * 64 + i * 16 + orow) * N + (bn + wc * 64 + j * 16 + ocol);
#pragma unroll
            for (int r = 0; r < 4; ++r) {
                if constexpr (BF16_OUT)
                    ((unsigned short*)Cv)[base + (size_t)r * N] = f2bf(acc[i][j][r]);
                else
                    ((float*)Cv)[base + (size_t)r * N] = acc[i][j][r];
            }
        }
}

// ---------------------------------------------------------------------------
// Streaming per-tile top-4 -- branchless packed-key argmax (r7, validated).
// ---------------------------------------------------------------------------
__global__ __launch_bounds__(256)
void aux_pass(const unsigned short* __restrict__ scoresb,
              float4* __restrict__ aux) {
    const int tid  = threadIdx.x;
    const int lane = tid & 63;
    const int w    = tid >> 6;
    const int t    = blockIdx.x * 4 + w;
    const unsigned short* srow = scoresb + (size_t)t * NSLOTS;

#pragma unroll
    for (int j = 0; j < 8; ++j) {
        const int c0 = j * 512 + lane * 8;   // tile = j*4 + (lane>>4)
        const u16x8 s8 = *(const u16x8*)(srow + c0);
        unsigned int k[8];
#pragma unroll
        for (int e = 0; e < 8; ++e) {
            const unsigned int b   = (unsigned int)s8[e] & 0xffffu;
            const unsigned int ord = b ^ ((b & 0x8000u) ? 0xffffu : 0x8000u);
            k[e] = (ord << 12) | (4095u - (unsigned int)(c0 + e));
        }
        unsigned int win[4];
#pragma unroll
        for (int p = 0; p < 4; ++p) {
            unsigned int m01 = max(k[0], k[1]), m23 = max(k[2], k[3]);
            unsigned int m45 = max(k[4], k[5]), m67 = max(k[6], k[7]);
            unsigned int m = max(max(m01, m23), max(m45, m67));
#pragma unroll
            for (int off = 1; off < 16; off <<= 1)
                m = max(m, (unsigned int)__shfl_xor((int)m, off));
            win[p] = m;
#pragma unroll
            for (int e = 0; e < 8; ++e) k[e] = (k[e] == m) ? 0u : k[e];
        }
        if ((lane & 15) == 0) {
            float vv[4]; int id[4];
#pragma unroll
            for (int p = 0; p < 4; ++p) {
                const unsigned int ord = win[p] >> 12;
                const unsigned int b =
                    (ord & 0x8000u) ? (ord ^ 0x8000u) : (~ord & 0xffffu);
                vv[p] = bf2f((unsigned short)b);
                id[p] = 4095 - (int)(win[p] & 0xfffu);
            }
            const int tile = j * 4 + (lane >> 4);
            float4* dst = aux + ((size_t)t * NTILES + tile) * 2;
            float4 o1, o2;
            o1.x = vv[0]; o1.y = __int_as_float(id[0]);
            o1.z = vv[1]; o1.w = __int_as_float(id[1]);
            o2.x = vv[2]; o2.y = __int_as_float(id[2]);
            o2.z = vv[3]; o2.w = __int_as_float(id[3]);
            dst[0] = o1;
            dst[1] = o2;
        }
    }
}

// ---------------------------------------------------------------------------
// Wave-per-row refine: merge aux -> thresh -> candidates (aux + rare flagged
// tile rescan) -> EXACT fp32 re-score (identical math, rounds 2-10) ->
// softmax -> gather.  UNCHANGED from r7.
// ---------------------------------------------------------------------------
__global__ __launch_bounds__(256)
void topk_refine(const float4* __restrict__ aux,
                 const unsigned short* __restrict__ scoresb,
                 const float* __restrict__ x,
                 const float* __restrict__ KW,
                 const unsigned short* __restrict__ svb,
                 unsigned short* __restrict__ retr) {
    const int tid  = threadIdx.x;
    const int lane = tid & 63;
    const int w    = tid >> 6;
    const int t    = blockIdx.x * 4 + w;

    const float* xrow = x + (size_t)t * D_DIM + lane * 4;
    float4 xv[8];
#pragma unroll
    for (int i = 0; i < 8; ++i) xv[i] = *(const float4*)(xrow + 256 * i);

    __shared__ int          cand[4][CAND_MAX];
    __shared__ int          ncand[4];
    __shared__ unsigned int flags[4];
    if (lane == 0) { ncand[w] = 0; flags[w] = 0; }
    __syncthreads();

    const float4 e2 = aux[(size_t)t * 64 + lane];
    float v0 = -INFINITY, v1 = -INFINITY, v2 = -INFINITY, v3 = -INFINITY;
    int   i0 = 0x7fffffff, i1 = 0x7fffffff, i2 = 0x7fffffff, i3 = 0x7fffffff;
    cand_insert(e2.x, __float_as_int(e2.y), v0, i0, v1, i1, v2, i2, v3, i3);
    cand_insert(e2.z, __float_as_int(e2.w), v0, i0, v1, i1, v2, i2, v3, i3);
#pragma unroll
    for (int off = 1; off < 64; off <<= 1) {
        float s0 = __shfl_xor(v0, off), s1 = __shfl_xor(v1, off);
        float s2 = __shfl_xor(v2, off), s3 = __shfl_xor(v3, off);
        int   j0 = __shfl_xor(i0, off), j1 = __shfl_xor(i1, off);
        int   j2 = __shfl_xor(i2, off), j3 = __shfl_xor(i3, off);
        cand_insert(s0, j0, v0, i0, v1, i1, v2, i2, v3, i3);
        cand_insert(s1, j1, v0, i0, v1, i1, v2, i2, v3, i3);
        cand_insert(s2, j2, v0, i0, v1, i1, v2, i2, v3, i3);
        cand_insert(s3, j3, v0, i0, v1, i1, v2, i2, v3, i3);
    }
    const float thresh = v3 - MARGIN;

    if ((lane & 1) && e2.z >= thresh)
        atomicOr(&flags[w], 1u << (lane >> 1));
    __syncthreads();
    const unsigned int fl = flags[w];

    const int mytile = lane >> 1;
    if (!((fl >> mytile) & 1u)) {
        if (e2.x >= thresh) {
            int p = atomicAdd(&ncand[w], 1);
            if (p < CAND_MAX) cand[w][p] = __float_as_int(e2.y);
        }
        if (e2.z >= thresh) {
            int p = atomicAdd(&ncand[w], 1);
            if (p < CAND_MAX) cand[w][p] = __float_as_int(e2.w);
        }
    }
    unsigned int fscan = fl;
    while (fscan) {
        const int tb = __ffs(fscan) - 1;
        fscan &= fscan - 1;
        const unsigned short* srow =
            scoresb + (size_t)t * NSLOTS + tb * 128 + lane * 2;
        const unsigned short s0 = srow[0], s1 = srow[1];
        if (bf2f(s0) >= thresh) {
            int p = atomicAdd(&ncand[w], 1);
            if (p < CAND_MAX) cand[w][p] = tb * 128 + lane * 2;
        }
        if (bf2f(s1) >= thresh) {
            int p = atomicAdd(&ncand[w], 1);
            if (p < CAND_MAX) cand[w][p] = tb * 128 + lane * 2 + 1;
        }
    }
    __syncthreads();
    const int nc = min(ncand[w], CAND_MAX);

    float r0 = -INFINITY, r1 = -INFINITY, r2 = -INFINITY, r3 = -INFINITY;
    int   q0 = 0x7fffffff, q1 = 0x7fffffff, q2 = 0x7fffffff, q3 = 0x7fffffff;
    for (int c = 0; c < nc; ++c) {
        const int slot = cand[w][c];
        const float* kr = KW + (size_t)slot * D_DIM + lane * 4;
        float p = 0.0f;
#pragma unroll
        for (int i = 0; i < 8; ++i) {
            const float4 k4 = *(const float4*)(kr + 256 * i);
            p = fmaf(xv[i].x, k4.x, p);
            p = fmaf(xv[i].y, k4.y, p);
            p = fmaf(xv[i].z, k4.z, p);
            p = fmaf(xv[i].w, k4.w, p);
        }
#pragma unroll
        for (int off = 1; off < 64; off <<= 1) p += __shfl_xor(p, off);
        cand_insert(p, slot, r0, q0, r1, q1, r2, q2, r3, q3);
    }

    const float e1s = expf(SCALE * (r1 - r0));
    const float e2s = expf(SCALE * (r2 - r0));
    const float e3s = expf(SCALE * (r3 - r0));
    const float inv = 1.0f / (1.0f + e1s + e2s + e3s);
    const float w0s = inv, w1s = e1s * inv, w2s = e2s * inv, w3s = e3s * inv;

    const unsigned short* p0 = svb + (size_t)q0 * D_DIM;
    const unsigned short* p1 = svb + (size_t)q1 * D_DIM;
    const unsigned short* p2 = svb + (size_t)q2 * D_DIM;
    const unsigned short* p3 = svb + (size_t)q3 * D_DIM;
    unsigned short* orow = retr + (size_t)t * D_DIM;
#pragma unroll
    for (int i = 0; i < 4; ++i) {
        const int d0 = lane * 8 + 512 * i;
        u16x8 a0 = *(const u16x8*)(p0 + d0);
        u16x8 a1 = *(const u16x8*)(p1 + d0);
        u16x8 a2 = *(const u16x8*)(p2 + d0);
        u16x8 a3 = *(const u16x8*)(p3 + d0);
        u16x8 o;
#pragma unroll
        for (int e = 0; e < 8; ++e) {
            float s = w0s * bf2f(a0[e]) + w1s * bf2f(a1[e]) +
                      w2s * bf2f(a2[e]) + w3s * bf2f(a3[e]);
            o[e] = f2bf(s);
        }
        *(u16x8*)(orow + d0) = o;
    }
}

// ---------------------------------------------------------------------------
extern "C" void kernel_launch(void* const* d_in, const int* in_sizes, int n_in,
                              void* d_out, int out_size, void* d_ws, size_t ws_size,
                              hipStream_t stream) {
    const float* x    = (const float*)d_in[0];
    const float* sk   = (const float*)d_in[1];
    const float* sv   = (const float*)d_in[2];
    const float* wq   = (const float*)d_in[3];
    const float* wout = (const float*)d_in[4];

    // workspace layout (369.1 MB; r1 proved ws >= 402.6 MB)
    char* base = (char*)d_ws;
    unsigned short* scoresb = (unsigned short*)base;              // 134.2 MB
    float*          KW      = (float*)(base + 134217728);         //  33.55 MB
    unsigned short* kwb     = (unsigned short*)(base + 167772160);//  16.78 MB
    unsigned short* woutb   = (unsigned short*)(base + 184549376);//   8.39 MB
    unsigned short* xb      = (unsigned short*)(base + 192937984);//  67.11 MB (reused as retr)
    unsigned short* svb     = (unsigned short*)(base + 260046848);//  16.78 MB
    float4*         aux     = (float4*)(base + 276824064);        //  16.78 MB
    unsigned short* skh     = (unsigned short*)(base + 293601280);//  16.78 MB
    unsigned short* skm     = (unsigned short*)(base + 310378496);//  16.78 MB
    unsigned short* skl     = (unsigned short*)(base + 327155712);//  16.78 MB
    unsigned short* wqth    = (unsigned short*)(base + 343932928);//   8.39 MB
    unsigned short* wqtm    = (unsigned short*)(base + 352321536);//   8.39 MB
    unsigned short* wqtl    = (unsigned short*)(base + 360710144);//   8.39 MB

    const dim3 blk(256);

    // 3-way bf16 splits: SK (linear) and Wq (transposed)
    split3_lin<<<dim3((NSLOTS * (size_t)D_DIM) / 1024), blk, 0, stream>>>(
        sk, skh, skm, skl);
    split3_wqT<<<dim3(D_DIM / 32, D_DIM / 32), blk, 0, stream>>>(
        wq, wqth, wqtm, wqtl);

    // bf16 copies
    cvt_f32_bf16<<<dim3((BT_DIM * (size_t)D_DIM) / 2048), blk, 0, stream>>>(x, xb);
    cvt_f32_bf16<<<dim3((D_DIM * (size_t)D_DIM) / 2048), blk, 0, stream>>>(wout, woutb);
    cvt_f32_bf16<<<dim3((NSLOTS * (size_t)D_DIM) / 2048), blk, 0, stream>>>(sv, svb);

    // KW (fp32) + kwb (bf16) via 6-product split-bf16 MFMA
    gemm_kw_mfma6<<<dim3(D_DIM / 128, NSLOTS / 128), blk, 0, stream>>>(
        skh, skm, skl, wqth, wqtm, wqtl, KW, kwb, NSLOTS, D_DIM, D_DIM);

    // approx scores (bf16 out) = xb @ kwb^T
    gemm_bf16_abt<true><<<dim3(NSLOTS / 128, BT_DIM / 128), blk, 0, stream>>>(
        xb, kwb, scoresb, BT_DIM, NSLOTS, D_DIM);

    // per-tile top-4 summary (branchless packed-key argmax)
    aux_pass<<<dim3(BT_DIM / 4), blk, 0, stream>>>(scoresb, aux);

    // exact top-4 via aux + margin-refine; writes retrieved (bf16) over xb
    topk_refine<<<dim3(BT_DIM / 4), blk, 0, stream>>>(
        aux, scoresb, x, KW, svb, xb);

    // out = retrieved @ Wout^T  (fp32 out)
    gemm_bf16_abt<false><<<dim3(D_DIM / 128, BT_DIM / 128), blk, 0, stream>>>(
        xb, woutb, (float*)d_out, BT_DIM, D_DIM, D_DIM);
}

// Round 13
// 989.067 us; speedup vs baseline: 1.4422x; 1.0779x over previous
//
#include <hip/hip_runtime.h>
#include <math.h>

#define D_DIM    2048
#define BT_DIM   16384   // B*T
#define NSLOTS   4096
#define SCALE    0.02209708691207961f  // 1/sqrt(2048)
#define MARGIN   0.02f
#define CAND_MAX 16

typedef __attribute__((ext_vector_type(8))) short bf16x8;
typedef __attribute__((ext_vector_type(4))) float f32x4;
typedef __attribute__((ext_vector_type(8))) unsigned short u16x8;
typedef __attribute__((ext_vector_type(4))) unsigned short u16x4;

__device__ __forceinline__ unsigned short f2bf(float f) {
    unsigned int u = __float_as_uint(f);
    return (unsigned short)((u + 0x7fffu + ((u >> 16) & 1u)) >> 16);
}
__device__ __forceinline__ float bf2f(unsigned short s) {
    return __uint_as_float(((unsigned int)s) << 16);
}

__device__ __forceinline__ void async_cp16(const void* g, void* l) {
    __builtin_amdgcn_global_load_lds(
        (const __attribute__((address_space(1))) void*)g,
        (__attribute__((address_space(3))) void*)l, 16, 0, 0);
}

// ---------------------------------------------------------------------------
// top-4 helpers (jax semantics: val desc, idx asc) -- used in exact re-score
// ---------------------------------------------------------------------------
__device__ __forceinline__ bool cand_better(float v, int i, float v2, int i2) {
    return (v > v2) || (v == v2 && i < i2);
}

__device__ __forceinline__ void cand_insert(float v, int idx,
                                            float& v0, int& i0, float& v1, int& i1,
                                            float& v2, int& i2, float& v3, int& i3) {
    if (cand_better(v, idx, v3, i3)) {
        if (cand_better(v, idx, v0, i0)) {
            v3 = v2; i3 = i2; v2 = v1; i2 = i1; v1 = v0; i1 = i0; v0 = v; i0 = idx;
        } else if (cand_better(v, idx, v1, i1)) {
            v3 = v2; i3 = i2; v2 = v1; i2 = i1; v1 = v; i1 = idx;
        } else if (cand_better(v, idx, v2, i2)) {
            v3 = v2; i3 = i2; v2 = v; i2 = idx;
        } else {
            v3 = v; i3 = idx;
        }
    }
}

// ---------------------------------------------------------------------------
// 3-way bf16 split: v = h + m + l (each bf16, residual ~2^-27 |v|)
// ---------------------------------------------------------------------------
__device__ __forceinline__ void split3v(float v, unsigned short& h,
                                        unsigned short& m, unsigned short& l) {
    h = f2bf(v);
    const float r1 = v - bf2f(h);
    m = f2bf(r1);
    l = f2bf(r1 - bf2f(m));
}

// SK -> 3 bf16 component arrays (linear, 4 elems/thread)
__global__ __launch_bounds__(256)
void split3_lin(const float* __restrict__ in, unsigned short* __restrict__ oh,
                unsigned short* __restrict__ om, unsigned short* __restrict__ ol) {
    const size_t i = ((size_t)blockIdx.x * 256 + threadIdx.x) * 4;
    const float4 v = *(const float4*)(in + i);
    u16x4 h, m, l;
    unsigned short th, tm, tl;
    split3v(v.x, th, tm, tl); h[0] = th; m[0] = tm; l[0] = tl;
    split3v(v.y, th, tm, tl); h[1] = th; m[1] = tm; l[1] = tl;
    split3v(v.z, th, tm, tl); h[2] = th; m[2] = tm; l[2] = tl;
    split3v(v.w, th, tm, tl); h[3] = th; m[3] = tm; l[3] = tl;
    *(u16x4*)(oh + i) = h;
    *(u16x4*)(om + i) = m;
    *(u16x4*)(ol + i) = l;
}

// Wq[e][d] -> transposed 3 bf16 component arrays out[d][e]  (32x32 LDS tiles)
__global__ __launch_bounds__(256)
void split3_wqT(const float* __restrict__ W, unsigned short* __restrict__ th,
                unsigned short* __restrict__ tm, unsigned short* __restrict__ tl) {
    __shared__ float tile[32][33];
    const int tx  = threadIdx.x & 31;
    const int ty4 = (threadIdx.x >> 5) * 4;
    const int e0  = blockIdx.y * 32;
    const int d0  = blockIdx.x * 32;
#pragma unroll
    for (int r = 0; r < 4; ++r)
        tile[ty4 + r][tx] = W[(size_t)(e0 + ty4 + r) * D_DIM + (d0 + tx)];
    __syncthreads();
#pragma unroll
    for (int r = 0; r < 4; ++r) {
        const float v = tile[tx][ty4 + r];   // = W[e0+tx][d0+ty4+r]
        unsigned short h, m, l;
        split3v(v, h, m, l);
        const size_t o = (size_t)(d0 + ty4 + r) * D_DIM + (e0 + tx);
        th[o] = h; tm[o] = m; tl[o] = l;
    }
}

// ---------------------------------------------------------------------------
// fp32 -> bf16 elementwise (8 elems/thread), exact grid
// ---------------------------------------------------------------------------
__global__ __launch_bounds__(256)
void cvt_f32_bf16(const float* __restrict__ in, unsigned short* __restrict__ out) {
    const size_t i = ((size_t)blockIdx.x * 256 + threadIdx.x) * 8;
    float4 a = *(const float4*)(in + i);
    float4 b = *(const float4*)(in + i + 4);
    u16x8 o;
    o[0] = f2bf(a.x); o[1] = f2bf(a.y); o[2] = f2bf(a.z); o[3] = f2bf(a.w);
    o[4] = f2bf(b.x); o[5] = f2bf(b.y); o[6] = f2bf(b.z); o[7] = f2bf(b.w);
    *(u16x8*)(out + i) = o;
}

// ---------------------------------------------------------------------------
// KW = SK @ Wq via 6-product split-bf16 MFMA (fp32-grade) -- r12 validated.
// ---------------------------------------------------------------------------
__global__ __launch_bounds__(256)
void gemm_kw_mfma6(const unsigned short* __restrict__ Ah,
                   const unsigned short* __restrict__ Am,
                   const unsigned short* __restrict__ Al,
                   const unsigned short* __restrict__ Bh,
                   const unsigned short* __restrict__ Bm,
                   const unsigned short* __restrict__ Bl,
                   float* __restrict__ KW, unsigned short* __restrict__ kwb,
                   int M, int N, int K) {
    __shared__ __align__(16) unsigned short AldsH[128 * 32];
    __shared__ __align__(16) unsigned short AldsM[128 * 32];
    __shared__ __align__(16) unsigned short AldsL[128 * 32];
    __shared__ __align__(16) unsigned short BldsH[128 * 32];
    __shared__ __align__(16) unsigned short BldsM[128 * 32];
    __shared__ __align__(16) unsigned short BldsL[128 * 32];

    const int tid  = threadIdx.x;
    const int lane = tid & 63;
    const int w    = tid >> 6;
    const int wr   = w >> 1, wc = w & 1;
    const int bmr  = blockIdx.y * 128;
    const int bnc  = blockIdx.x * 128;

    const int srow = lane >> 2;
    const int skch = (lane & 3) ^ ((lane >> 3) & 3);
    const int c0 = w, c1 = w + 4;
    size_t oA0 = (size_t)(bmr + c0 * 16 + srow) * K + skch * 8;
    size_t oA1 = (size_t)(bmr + c1 * 16 + srow) * K + skch * 8;
    size_t oB0 = (size_t)(bnc + c0 * 16 + srow) * K + skch * 8;
    size_t oB1 = (size_t)(bnc + c1 * 16 + srow) * K + skch * 8;
    char* lAh0 = (char*)AldsH + c0 * 1024;  char* lAh1 = (char*)AldsH + c1 * 1024;
    char* lAm0 = (char*)AldsM + c0 * 1024;  char* lAm1 = (char*)AldsM + c1 * 1024;
    char* lAl0 = (char*)AldsL + c0 * 1024;  char* lAl1 = (char*)AldsL + c1 * 1024;
    char* lBh0 = (char*)BldsH + c0 * 1024;  char* lBh1 = (char*)BldsH + c1 * 1024;
    char* lBm0 = (char*)BldsM + c0 * 1024;  char* lBm1 = (char*)BldsM + c1 * 1024;
    char* lBl0 = (char*)BldsL + c0 * 1024;  char* lBl1 = (char*)BldsL + c1 * 1024;

    const int kbyte = (((lane >> 4) ^ ((lane >> 1) & 3)) << 4);
    const int rA = wr * 64 + (lane & 15);
    const int rB = wc * 64 + (lane & 15);

    f32x4 acc[4][4] = {};

    for (int kt = 0; kt < K; kt += 32) {
        async_cp16(Ah + oA0, lAh0);  async_cp16(Ah + oA1, lAh1);
        async_cp16(Am + oA0, lAm0);  async_cp16(Am + oA1, lAm1);
        async_cp16(Al + oA0, lAl0);  async_cp16(Al + oA1, lAl1);
        async_cp16(Bh + oB0, lBh0);  async_cp16(Bh + oB1, lBh1);
        async_cp16(Bm + oB0, lBm0);  async_cp16(Bm + oB1, lBm1);
        async_cp16(Bl + oB0, lBl0);  async_cp16(Bl + oB1, lBl1);
        oA0 += 32; oA1 += 32; oB0 += 32; oB1 += 32;
        __syncthreads();

        bf16x8 afh[4], afm[4], afl[4], bfh[4], bfm[4], bfl[4];
#pragma unroll
        for (int i = 0; i < 4; ++i) {
            const int ar = (rA + i * 16) * 64 + kbyte;
            afh[i] = *(const bf16x8*)((const char*)AldsH + ar);
            afm[i] = *(const bf16x8*)((const char*)AldsM + ar);
            afl[i] = *(const bf16x8*)((const char*)AldsL + ar);
            const int br = (rB + i * 16) * 64 + kbyte;
            bfh[i] = *(const bf16x8*)((const char*)BldsH + br);
            bfm[i] = *(const bf16x8*)((const char*)BldsM + br);
            bfl[i] = *(const bf16x8*)((const char*)BldsL + br);
        }
#pragma unroll
        for (int i = 0; i < 4; ++i)
#pragma unroll
            for (int j = 0; j < 4; ++j) {
                f32x4 c = acc[i][j];
                c = __builtin_amdgcn_mfma_f32_16x16x32_bf16(afh[i], bfh[j], c, 0, 0, 0);
                c = __builtin_amdgcn_mfma_f32_16x16x32_bf16(afh[i], bfm[j], c, 0, 0, 0);
                c = __builtin_amdgcn_mfma_f32_16x16x32_bf16(afm[i], bfh[j], c, 0, 0, 0);
                c = __builtin_amdgcn_mfma_f32_16x16x32_bf16(afm[i], bfm[j], c, 0, 0, 0);
                c = __builtin_amdgcn_mfma_f32_16x16x32_bf16(afh[i], bfl[j], c, 0, 0, 0);
                c = __builtin_amdgcn_mfma_f32_16x16x32_bf16(afl[i], bfh[j], c, 0, 0, 0);
                acc[i][j] = c;
            }
        __syncthreads();
    }

    const int orow = (lane >> 4) * 4;
    const int ocol = lane & 15;
#pragma unroll
    for (int i = 0; i < 4; ++i)
#pragma unroll
        for (int j = 0; j < 4; ++j) {
            const size_t base =
                (size_t)(bmr + wr * 64 + i * 16 + orow) * N + (bnc + wc * 64 + j * 16 + ocol);
#pragma unroll
            for (int r = 0; r < 4; ++r) {
                const float v = acc[i][j][r];
                KW[base + (size_t)r * N]  = v;
                kwb[base + (size_t)r * N] = f2bf(v);
            }
        }
}

// ---------------------------------------------------------------------------
// bf16 MFMA GEMM: C[M,N] = A[M,K] @ B[N,K]^T; C fp32 or bf16 (template).
// r7 exact baseline (no swizzle, no epilogue fusion -- r8/r10 lessons).
// ---------------------------------------------------------------------------
template <bool BF16_OUT>
__global__ __launch_bounds__(256)
void gemm_bf16_abt(const unsigned short* __restrict__ A,
                   const unsigned short* __restrict__ B,
                   void* __restrict__ Cv, int M, int N, int K) {
    __shared__ __align__(16) unsigned short Alds[128 * 32];
    __shared__ __align__(16) unsigned short Blds[128 * 32];

    const int tid  = threadIdx.x;
    const int lane = tid & 63;
    const int w    = tid >> 6;
    const int wr   = w >> 1, wc = w & 1;
    const int bm   = blockIdx.y * 128;
    const int bn   = blockIdx.x * 128;

    const int srow = lane >> 2;
    const int skch = (lane & 3) ^ ((lane >> 3) & 3);
    const int c0 = w, c1 = w + 4;
    const unsigned short* gA0 = A + (size_t)(bm + c0 * 16 + srow) * K + skch * 8;
    const unsigned short* gA1 = A + (size_t)(bm + c1 * 16 + srow) * K + skch * 8;
    const unsigned short* gB0 = B + (size_t)(bn + c0 * 16 + srow) * K + skch * 8;
    const unsigned short* gB1 = B + (size_t)(bn + c1 * 16 + srow) * K + skch * 8;
    char* lA0 = (char*)Alds + c0 * 1024;
    char* lA1 = (char*)Alds + c1 * 1024;
    char* lB0 = (char*)Blds + c0 * 1024;
    char* lB1 = (char*)Blds + c1 * 1024;

    const int kbyte = (((lane >> 4) ^ ((lane >> 1) & 3)) << 4);
    const int rA = wr * 64 + (lane & 15);
    const int rB = wc * 64 + (lane & 15);

    f32x4 acc[4][4] = {};

    for (int kt = 0; kt < K; kt += 32) {
        async_cp16(gA0, lA0);
        async_cp16(gA1, lA1);
        async_cp16(gB0, lB0);
        async_cp16(gB1, lB1);
        gA0 += 32; gA1 += 32; gB0 += 32; gB1 += 32;
        __syncthreads();

        bf16x8 a[4], b[4];
#pragma unroll
        for (int i = 0; i < 4; ++i) {
            a[i] = *(const bf16x8*)((const char*)Alds + (rA + i * 16) * 64 + kbyte);
            b[i] = *(const bf16x8*)((const char*)Blds + (rB + i * 16) * 64 + kbyte);
        }
#pragma unroll
        for (int i = 0; i < 4; ++i)
#pragma unroll
            for (int j = 0; j < 4; ++j)
                acc[i][j] = __builtin_amdgcn_mfma_f32_16x16x32_bf16(
                    a[i], b[j], acc[i][j], 0, 0, 0);
        __syncthreads();
    }

    const int orow = (lane >> 4) * 4;
    const int ocol = lane & 15;
#pragma unroll
    for (int i = 0; i < 4; ++i)
#pragma unroll
        for (int j = 0; j < 4; ++j) {
            const size_t base =
                (size_t)(bm + wr * 64 + i * 16 + orow) * N + (bn + wc * 64 + j * 16 + ocol);
#pragma unroll
            for (int r = 0; r < 4; ++r) {
                if constexpr (BF16_OUT)
                    ((unsigned short*)Cv)[base + (size_t)r * N] = f2bf(acc[i][j][r]);
                else
                    ((float*)Cv)[base + (size_t)r * N] = acc[i][j][r];
            }
        }
}

// ---------------------------------------------------------------------------
// Merged refine (r13): wave-per-row, whole row held as 64 packed keys/lane.
//   load scoresb row -> branchless top-4 (4x{tree-max + butterfly + mask})
//   -> thresh = 4th - MARGIN -> candidates = winners + key-scan >= thresh
//   (provably same candidate set as r7's aux+flagged construction:
//    both equal {slot : bf16score >= thresh})
//   -> EXACT fp32 re-score (identical math, rounds 2-12) -> softmax -> gather.
// Replaces aux_pass + aux buffer + flagged-rescan entirely.
// ---------------------------------------------------------------------------
__global__ __launch_bounds__(256)
void topk_refine(const unsigned short* __restrict__ scoresb,
                 const float* __restrict__ x,
                 const float* __restrict__ KW,
                 const unsigned short* __restrict__ svb,
                 unsigned short* __restrict__ retr) {
    const int tid  = threadIdx.x;
    const int lane = tid & 63;
    const int w    = tid >> 6;
    const int t    = blockIdx.x * 4 + w;
    const unsigned short* srow = scoresb + (size_t)t * NSLOTS;

    __shared__ int cand[4][CAND_MAX];
    __shared__ int ncand[4];

    // ---- load 64 bf16 scores/lane, build order-isomorphic packed keys
    unsigned int k[64];
#pragma unroll
    for (int j = 0; j < 8; ++j) {
        const int c0 = j * 512 + lane * 8;
        const u16x8 s8 = *(const u16x8*)(srow + c0);
#pragma unroll
        for (int e = 0; e < 8; ++e) {
            const unsigned int b   = (unsigned int)s8[e] & 0xffffu;
            const unsigned int ord = b ^ ((b & 0x8000u) ? 0xffffu : 0x8000u);
            k[j * 8 + e] = (ord << 12) | (4095u - (unsigned int)(c0 + e));
        }
    }

    // ---- branchless top-4 over the whole row
    unsigned int win[4];
#pragma unroll
    for (int p = 0; p < 4; ++p) {
        unsigned int a16[16];
#pragma unroll
        for (int e = 0; e < 16; ++e)
            a16[e] = max(max(k[e], k[e + 16]), max(k[e + 32], k[e + 48]));
        unsigned int a4[4];
#pragma unroll
        for (int e = 0; e < 4; ++e)
            a4[e] = max(max(a16[e], a16[e + 4]), max(a16[e + 8], a16[e + 12]));
        unsigned int m = max(max(a4[0], a4[1]), max(a4[2], a4[3]));
#pragma unroll
        for (int off = 1; off < 64; off <<= 1)
            m = max(m, (unsigned int)__shfl_xor((int)m, off));
        win[p] = m;
#pragma unroll
        for (int e = 0; e < 64; ++e) k[e] = (k[e] == m) ? 0u : k[e];
    }

    // decode 4th-best value -> threshold (winner ids for candidate seed)
    const unsigned int ord3 = win[3] >> 12;
    const unsigned int b3 =
        (ord3 & 0x8000u) ? (ord3 ^ 0x8000u) : (~ord3 & 0xffffu);
    const float thresh = bf2f((unsigned short)b3) - MARGIN;

    if (lane == 0) {
        ncand[w] = 4;
        cand[w][0] = 4095 - (int)(win[0] & 0xfffu);
        cand[w][1] = 4095 - (int)(win[1] & 0xfffu);
        cand[w][2] = 4095 - (int)(win[2] & 0xfffu);
        cand[w][3] = 4095 - (int)(win[3] & 0xfffu);
    }
    __syncthreads();

    // ---- margin candidates from remaining keys (winners are masked to 0;
    // masked keys decode to bf16 NaN -> compare false)
#pragma unroll
    for (int e = 0; e < 64; ++e) {
        const unsigned int kk  = k[e];
        const unsigned int ordv = kk >> 12;
        const unsigned int bv =
            (ordv & 0x8000u) ? (ordv ^ 0x8000u) : (~ordv & 0xffffu);
        if (bf2f((unsigned short)bv) >= thresh) {
            int p = atomicAdd(&ncand[w], 1);
            if (p < CAND_MAX) cand[w][p] = 4095 - (int)(kk & 0xfffu);
        }
    }
    __syncthreads();
    const int nc = min(ncand[w], CAND_MAX);

    // ---- exact fp32 re-score (IDENTICAL math to rounds 2-12 validated path)
    const float* xrow = x + (size_t)t * D_DIM + lane * 4;
    float4 xv[8];
#pragma unroll
    for (int i = 0; i < 8; ++i) xv[i] = *(const float4*)(xrow + 256 * i);

    float r0 = -INFINITY, r1 = -INFINITY, r2 = -INFINITY, r3 = -INFINITY;
    int   q0 = 0x7fffffff, q1 = 0x7fffffff, q2 = 0x7fffffff, q3 = 0x7fffffff;
    for (int c = 0; c < nc; ++c) {
        const int slot = cand[w][c];
        const float* kr = KW + (size_t)slot * D_DIM + lane * 4;
        float p = 0.0f;
#pragma unroll
        for (int i = 0; i < 8; ++i) {
            const float4 k4 = *(const float4*)(kr + 256 * i);
            p = fmaf(xv[i].x, k4.x, p);
            p = fmaf(xv[i].y, k4.y, p);
            p = fmaf(xv[i].z, k4.z, p);
            p = fmaf(xv[i].w, k4.w, p);
        }
#pragma unroll
        for (int off = 1; off < 64; off <<= 1) p += __shfl_xor(p, off);
        cand_insert(p, slot, r0, q0, r1, q1, r2, q2, r3, q3);
    }

    // ---- softmax over scaled top-4 (r0 is max)
    const float e1s = expf(SCALE * (r1 - r0));
    const float e2s = expf(SCALE * (r2 - r0));
    const float e3s = expf(SCALE * (r3 - r0));
    const float inv = 1.0f / (1.0f + e1s + e2s + e3s);
    const float w0s = inv, w1s = e1s * inv, w2s = e2s * inv, w3s = e3s * inv;

    // ---- gather bf16 SV rows, weighted sum, write retr (bf16)
    const unsigned short* p0 = svb + (size_t)q0 * D_DIM;
    const unsigned short* p1 = svb + (size_t)q1 * D_DIM;
    const unsigned short* p2 = svb + (size_t)q2 * D_DIM;
    const unsigned short* p3 = svb + (size_t)q3 * D_DIM;
    unsigned short* orow = retr + (size_t)t * D_DIM;
#pragma unroll
    for (int i = 0; i < 4; ++i) {
        const int d0 = lane * 8 + 512 * i;
        u16x8 a0 = *(const u16x8*)(p0 + d0);
        u16x8 a1 = *(const u16x8*)(p1 + d0);
        u16x8 a2 = *(const u16x8*)(p2 + d0);
        u16x8 a3 = *(const u16x8*)(p3 + d0);
        u16x8 o;
#pragma unroll
        for (int e = 0; e < 8; ++e) {
            float s = w0s * bf2f(a0[e]) + w1s * bf2f(a1[e]) +
                      w2s * bf2f(a2[e]) + w3s * bf2f(a3[e]);
            o[e] = f2bf(s);
        }
        *(u16x8*)(orow + d0) = o;
    }
}

// ---------------------------------------------------------------------------
extern "C" void kernel_launch(void* const* d_in, const int* in_sizes, int n_in,
                              void* d_out, int out_size, void* d_ws, size_t ws_size,
                              hipStream_t stream) {
    const float* x    = (const float*)d_in[0];
    const float* sk   = (const float*)d_in[1];
    const float* sv   = (const float*)d_in[2];
    const float* wq   = (const float*)d_in[3];
    const float* wout = (const float*)d_in[4];

    // workspace layout (369.1 MB; r1 proved ws >= 402.6 MB)
    char* base = (char*)d_ws;
    unsigned short* scoresb = (unsigned short*)base;              // 134.2 MB
    float*          KW      = (float*)(base + 134217728);         //  33.55 MB
    unsigned short* kwb     = (unsigned short*)(base + 167772160);//  16.78 MB
    unsigned short* woutb   = (unsigned short*)(base + 184549376);//   8.39 MB
    unsigned short* xb      = (unsigned short*)(base + 192937984);//  67.11 MB (reused as retr)
    unsigned short* svb     = (unsigned short*)(base + 260046848);//  16.78 MB
    unsigned short* skh     = (unsigned short*)(base + 293601280);//  16.78 MB
    unsigned short* skm     = (unsigned short*)(base + 310378496);//  16.78 MB
    unsigned short* skl     = (unsigned short*)(base + 327155712);//  16.78 MB
    unsigned short* wqth    = (unsigned short*)(base + 343932928);//   8.39 MB
    unsigned short* wqtm    = (unsigned short*)(base + 352321536);//   8.39 MB
    unsigned short* wqtl    = (unsigned short*)(base + 360710144);//   8.39 MB

    const dim3 blk(256);

    // 3-way bf16 splits: SK (linear) and Wq (transposed)
    split3_lin<<<dim3((NSLOTS * (size_t)D_DIM) / 1024), blk, 0, stream>>>(
        sk, skh, skm, skl);
    split3_wqT<<<dim3(D_DIM / 32, D_DIM / 32), blk, 0, stream>>>(
        wq, wqth, wqtm, wqtl);

    // bf16 copies
    cvt_f32_bf16<<<dim3((BT_DIM * (size_t)D_DIM) / 2048), blk, 0, stream>>>(x, xb);
    cvt_f32_bf16<<<dim3((D_DIM * (size_t)D_DIM) / 2048), blk, 0, stream>>>(wout, woutb);
    cvt_f32_bf16<<<dim3((NSLOTS * (size_t)D_DIM) / 2048), blk, 0, stream>>>(sv, svb);

    // KW (fp32) + kwb (bf16) via 6-product split-bf16 MFMA (r12 validated)
    gemm_kw_mfma6<<<dim3(D_DIM / 128, NSLOTS / 128), blk, 0, stream>>>(
        skh, skm, skl, wqth, wqtm, wqtl, KW, kwb, NSLOTS, D_DIM, D_DIM);

    // approx scores (bf16 out) = xb @ kwb^T
    gemm_bf16_abt<true><<<dim3(NSLOTS / 128, BT_DIM / 128), blk, 0, stream>>>(
        xb, kwb, scoresb, BT_DIM, NSLOTS, D_DIM);

    // merged top-4: in-register row keys + exact refine; writes retr over xb
    topk_refine<<<dim3(BT_DIM / 4), blk, 0, stream>>>(
        scoresb, x, KW, svb, xb);

    // out = retrieved @ Wout^T  (fp32 out)
    gemm_bf16_abt<false><<<dim3(D_DIM / 128, BT_DIM / 128), blk, 0, stream>>>(
        xb, woutb, (float*)d_out, BT_DIM, D_DIM, D_DIM);
}

// Round 14
// 892.767 us; speedup vs baseline: 1.5978x; 1.1079x over previous
//
#include <hip/hip_runtime.h>
#include <math.h>

#define D_DIM    2048
#define BT_DIM   16384   // B*T
#define NSLOTS   4096
#define SCALE    0.02209708691207961f  // 1/sqrt(2048)
#define MARGIN   0.02f
#define CAND_MAX 16

typedef __attribute__((ext_vector_type(8))) short bf16x8;
typedef __attribute__((ext_vector_type(4))) float f32x4;
typedef __attribute__((ext_vector_type(8))) unsigned short u16x8;
typedef __attribute__((ext_vector_type(4))) unsigned short u16x4;

__device__ __forceinline__ unsigned short f2bf(float f) {
    unsigned int u = __float_as_uint(f);
    return (unsigned short)((u + 0x7fffu + ((u >> 16) & 1u)) >> 16);
}
__device__ __forceinline__ float bf2f(unsigned short s) {
    return __uint_as_float(((unsigned int)s) << 16);
}

__device__ __forceinline__ void async_cp16(const void* g, void* l) {
    __builtin_amdgcn_global_load_lds(
        (const __attribute__((address_space(1))) void*)g,
        (__attribute__((address_space(3))) void*)l, 16, 0, 0);
}

// ---------------------------------------------------------------------------
// top-4 helpers (jax semantics: val desc, idx asc) -- used in exact re-score
// ---------------------------------------------------------------------------
__device__ __forceinline__ bool cand_better(float v, int i, float v2, int i2) {
    return (v > v2) || (v == v2 && i < i2);
}

__device__ __forceinline__ void cand_insert(float v, int idx,
                                            float& v0, int& i0, float& v1, int& i1,
                                            float& v2, int& i2, float& v3, int& i3) {
    if (cand_better(v, idx, v3, i3)) {
        if (cand_better(v, idx, v0, i0)) {
            v3 = v2; i3 = i2; v2 = v1; i2 = i1; v1 = v0; i1 = i0; v0 = v; i0 = idx;
        } else if (cand_better(v, idx, v1, i1)) {
            v3 = v2; i3 = i2; v2 = v1; i2 = i1; v1 = v; i1 = idx;
        } else if (cand_better(v, idx, v2, i2)) {
            v3 = v2; i3 = i2; v2 = v; i2 = idx;
        } else {
            v3 = v; i3 = idx;
        }
    }
}

// ---------------------------------------------------------------------------
// 3-way bf16 split: v = h + m + l (each bf16, residual ~2^-27 |v|)
// ---------------------------------------------------------------------------
__device__ __forceinline__ void split3v(float v, unsigned short& h,
                                        unsigned short& m, unsigned short& l) {
    h = f2bf(v);
    const float r1 = v - bf2f(h);
    m = f2bf(r1);
    l = f2bf(r1 - bf2f(m));
}

// SK -> 3 bf16 component arrays (linear, 4 elems/thread)
__global__ __launch_bounds__(256)
void split3_lin(const float* __restrict__ in, unsigned short* __restrict__ oh,
                unsigned short* __restrict__ om, unsigned short* __restrict__ ol) {
    const size_t i = ((size_t)blockIdx.x * 256 + threadIdx.x) * 4;
    const float4 v = *(const float4*)(in + i);
    u16x4 h, m, l;
    unsigned short th, tm, tl;
    split3v(v.x, th, tm, tl); h[0] = th; m[0] = tm; l[0] = tl;
    split3v(v.y, th, tm, tl); h[1] = th; m[1] = tm; l[1] = tl;
    split3v(v.z, th, tm, tl); h[2] = th; m[2] = tm; l[2] = tl;
    split3v(v.w, th, tm, tl); h[3] = th; m[3] = tm; l[3] = tl;
    *(u16x4*)(oh + i) = h;
    *(u16x4*)(om + i) = m;
    *(u16x4*)(ol + i) = l;
}

// Wq[e][d] -> transposed 3 bf16 component arrays out[d][e]  (32x32 LDS tiles)
__global__ __launch_bounds__(256)
void split3_wqT(const float* __restrict__ W, unsigned short* __restrict__ th,
                unsigned short* __restrict__ tm, unsigned short* __restrict__ tl) {
    __shared__ float tile[32][33];
    const int tx  = threadIdx.x & 31;
    const int ty4 = (threadIdx.x >> 5) * 4;
    const int e0  = blockIdx.y * 32;
    const int d0  = blockIdx.x * 32;
#pragma unroll
    for (int r = 0; r < 4; ++r)
        tile[ty4 + r][tx] = W[(size_t)(e0 + ty4 + r) * D_DIM + (d0 + tx)];
    __syncthreads();
#pragma unroll
    for (int r = 0; r < 4; ++r) {
        const float v = tile[tx][ty4 + r];   // = W[e0+tx][d0+ty4+r]
        unsigned short h, m, l;
        split3v(v, h, m, l);
        const size_t o = (size_t)(d0 + ty4 + r) * D_DIM + (e0 + tx);
        th[o] = h; tm[o] = m; tl[o] = l;
    }
}

// ---------------------------------------------------------------------------
// fp32 -> bf16 elementwise (8 elems/thread), exact grid
// ---------------------------------------------------------------------------
__global__ __launch_bounds__(256)
void cvt_f32_bf16(const float* __restrict__ in, unsigned short* __restrict__ out) {
    const size_t i = ((size_t)blockIdx.x * 256 + threadIdx.x) * 8;
    float4 a = *(const float4*)(in + i);
    float4 b = *(const float4*)(in + i + 4);
    u16x8 o;
    o[0] = f2bf(a.x); o[1] = f2bf(a.y); o[2] = f2bf(a.z); o[3] = f2bf(a.w);
    o[4] = f2bf(b.x); o[5] = f2bf(b.y); o[6] = f2bf(b.z); o[7] = f2bf(b.w);
    *(u16x8*)(out + i) = o;
}

// ---------------------------------------------------------------------------
// KW = SK @ Wq via 6-product split-bf16 MFMA (fp32-grade) -- r12 validated.
// ---------------------------------------------------------------------------
__global__ __launch_bounds__(256)
void gemm_kw_mfma6(const unsigned short* __restrict__ Ah,
                   const unsigned short* __restrict__ Am,
                   const unsigned short* __restrict__ Al,
                   const unsigned short* __restrict__ Bh,
                   const unsigned short* __restrict__ Bm,
                   const unsigned short* __restrict__ Bl,
                   float* __restrict__ KW, unsigned short* __restrict__ kwb,
                   int M, int N, int K) {
    __shared__ __align__(16) unsigned short AldsH[128 * 32];
    __shared__ __align__(16) unsigned short AldsM[128 * 32];
    __shared__ __align__(16) unsigned short AldsL[128 * 32];
    __shared__ __align__(16) unsigned short BldsH[128 * 32];
    __shared__ __align__(16) unsigned short BldsM[128 * 32];
    __shared__ __align__(16) unsigned short BldsL[128 * 32];

    const int tid  = threadIdx.x;
    const int lane = tid & 63;
    const int w    = tid >> 6;
    const int wr   = w >> 1, wc = w & 1;
    const int bmr  = blockIdx.y * 128;
    const int bnc  = blockIdx.x * 128;

    const int srow = lane >> 2;
    const int skch = (lane & 3) ^ ((lane >> 3) & 3);
    const int c0 = w, c1 = w + 4;
    size_t oA0 = (size_t)(bmr + c0 * 16 + srow) * K + skch * 8;
    size_t oA1 = (size_t)(bmr + c1 * 16 + srow) * K + skch * 8;
    size_t oB0 = (size_t)(bnc + c0 * 16 + srow) * K + skch * 8;
    size_t oB1 = (size_t)(bnc + c1 * 16 + srow) * K + skch * 8;
    char* lAh0 = (char*)AldsH + c0 * 1024;  char* lAh1 = (char*)AldsH + c1 * 1024;
    char* lAm0 = (char*)AldsM + c0 * 1024;  char* lAm1 = (char*)AldsM + c1 * 1024;
    char* lAl0 = (char*)AldsL + c0 * 1024;  char* lAl1 = (char*)AldsL + c1 * 1024;
    char* lBh0 = (char*)BldsH + c0 * 1024;  char* lBh1 = (char*)BldsH + c1 * 1024;
    char* lBm0 = (char*)BldsM + c0 * 1024;  char* lBm1 = (char*)BldsM + c1 * 1024;
    char* lBl0 = (char*)BldsL + c0 * 1024;  char* lBl1 = (char*)BldsL + c1 * 1024;

    const int kbyte = (((lane >> 4) ^ ((lane >> 1) & 3)) << 4);
    const int rA = wr * 64 + (lane & 15);
    const int rB = wc * 64 + (lane & 15);

    f32x4 acc[4][4] = {};

    for (int kt = 0; kt < K; kt += 32) {
        async_cp16(Ah + oA0, lAh0);  async_cp16(Ah + oA1, lAh1);
        async_cp16(Am + oA0, lAm0);  async_cp16(Am + oA1, lAm1);
        async_cp16(Al + oA0, lAl0);  async_cp16(Al + oA1, lAl1);
        async_cp16(Bh + oB0, lBh0);  async_cp16(Bh + oB1, lBh1);
        async_cp16(Bm + oB0, lBm0);  async_cp16(Bm + oB1, lBm1);
        async_cp16(Bl + oB0, lBl0);  async_cp16(Bl + oB1, lBl1);
        oA0 += 32; oA1 += 32; oB0 += 32; oB1 += 32;
        __syncthreads();

        bf16x8 afh[4], afm[4], afl[4], bfh[4], bfm[4], bfl[4];
#pragma unroll
        for (int i = 0; i < 4; ++i) {
            const int ar = (rA + i * 16) * 64 + kbyte;
            afh[i] = *(const bf16x8*)((const char*)AldsH + ar);
            afm[i] = *(const bf16x8*)((const char*)AldsM + ar);
            afl[i] = *(const bf16x8*)((const char*)AldsL + ar);
            const int br = (rB + i * 16) * 64 + kbyte;
            bfh[i] = *(const bf16x8*)((const char*)BldsH + br);
            bfm[i] = *(const bf16x8*)((const char*)BldsM + br);
            bfl[i] = *(const bf16x8*)((const char*)BldsL + br);
        }
#pragma unroll
        for (int i = 0; i < 4; ++i)
#pragma unroll
            for (int j = 0; j < 4; ++j) {
                f32x4 c = acc[i][j];
                c = __builtin_amdgcn_mfma_f32_16x16x32_bf16(afh[i], bfh[j], c, 0, 0, 0);
                c = __builtin_amdgcn_mfma_f32_16x16x32_bf16(afh[i], bfm[j], c, 0, 0, 0);
                c = __builtin_amdgcn_mfma_f32_16x16x32_bf16(afm[i], bfh[j], c, 0, 0, 0);
                c = __builtin_amdgcn_mfma_f32_16x16x32_bf16(afm[i], bfm[j], c, 0, 0, 0);
                c = __builtin_amdgcn_mfma_f32_16x16x32_bf16(afh[i], bfl[j], c, 0, 0, 0);
                c = __builtin_amdgcn_mfma_f32_16x16x32_bf16(afl[i], bfh[j], c, 0, 0, 0);
                acc[i][j] = c;
            }
        __syncthreads();
    }

    const int orow = (lane >> 4) * 4;
    const int ocol = lane & 15;
#pragma unroll
    for (int i = 0; i < 4; ++i)
#pragma unroll
        for (int j = 0; j < 4; ++j) {
            const size_t base =
                (size_t)(bmr + wr * 64 + i * 16 + orow) * N + (bnc + wc * 64 + j * 16 + ocol);
#pragma unroll
            for (int r = 0; r < 4; ++r) {
                const float v = acc[i][j][r];
                KW[base + (size_t)r * N]  = v;
                kwb[base + (size_t)r * N] = f2bf(v);
            }
        }
}

// ---------------------------------------------------------------------------
// bf16 MFMA GEMM: C[M,N] = A[M,K] @ B[N,K]^T; C fp32 or bf16 (template).
// r7 exact baseline (no swizzle, no epilogue fusion -- r8/r10 lessons).
// Used for: scores (bf16 out), SVW = SV @ Wout^T (fp32 out).
// ---------------------------------------------------------------------------
template <bool BF16_OUT>
__global__ __launch_bounds__(256)
void gemm_bf16_abt(const unsigned short* __restrict__ A,
                   const unsigned short* __restrict__ B,
                   void* __restrict__ Cv, int M, int N, int K) {
    __shared__ __align__(16) unsigned short Alds[128 * 32];
    __shared__ __align__(16) unsigned short Blds[128 * 32];

    const int tid  = threadIdx.x;
    const int lane = tid & 63;
    const int w    = tid >> 6;
    const int wr   = w >> 1, wc = w & 1;
    const int bm   = blockIdx.y * 128;
    const int bn   = blockIdx.x * 128;

    const int srow = lane >> 2;
    const int skch = (lane & 3) ^ ((lane >> 3) & 3);
    const int c0 = w, c1 = w + 4;
    const unsigned short* gA0 = A + (size_t)(bm + c0 * 16 + srow) * K + skch * 8;
    const unsigned short* gA1 = A + (size_t)(bm + c1 * 16 + srow) * K + skch * 8;
    const unsigned short* gB0 = B + (size_t)(bn + c0 * 16 + srow) * K + skch * 8;
    const unsigned short* gB1 = B + (size_t)(bn + c1 * 16 + srow) * K + skch * 8;
    char* lA0 = (char*)Alds + c0 * 1024;
    char* lA1 = (char*)Alds + c1 * 1024;
    char* lB0 = (char*)Blds + c0 * 1024;
    char* lB1 = (char*)Blds + c1 * 1024;

    const int kbyte = (((lane >> 4) ^ ((lane >> 1) & 3)) << 4);
    const int rA = wr * 64 + (lane & 15);
    const int rB = wc * 64 + (lane & 15);

    f32x4 acc[4][4] = {};

    for (int kt = 0; kt < K; kt += 32) {
        async_cp16(gA0, lA0);
        async_cp16(gA1, lA1);
        async_cp16(gB0, lB0);
        async_cp16(gB1, lB1);
        gA0 += 32; gA1 += 32; gB0 += 32; gB1 += 32;
        __syncthreads();

        bf16x8 a[4], b[4];
#pragma unroll
        for (int i = 0; i < 4; ++i) {
            a[i] = *(const bf16x8*)((const char*)Alds + (rA + i * 16) * 64 + kbyte);
            b[i] = *(const bf16x8*)((const char*)Blds + (rB + i * 16) * 64 + kbyte);
        }
#pragma unroll
        for (int i = 0; i < 4; ++i)
#pragma unroll
            for (int j = 0; j < 4; ++j)
                acc[i][j] = __builtin_amdgcn_mfma_f32_16x16x32_bf16(
                    a[i], b[j], acc[i][j], 0, 0, 0);
        __syncthreads();
    }

    const int orow = (lane >> 4) * 4;
    const int ocol = lane & 15;
#pragma unroll
    for (int i = 0; i < 4; ++i)
#pragma unroll
        for (int j = 0; j < 4; ++j) {
            const size_t base =
                (size_t)(bm + wr * 64 + i * 16 + orow) * N + (bn + wc * 64 + j * 16 + ocol);
#pragma unroll
            for (int r = 0; r < 4; ++r) {
                if constexpr (BF16_OUT)
                    ((unsigned short*)Cv)[base + (size_t)r * N] = f2bf(acc[i][j][r]);
                else
                    ((float*)Cv)[base + (size_t)r * N] = acc[i][j][r];
            }
        }
}

// ---------------------------------------------------------------------------
// Merged refine (r13 validated) + r14 SVW-gather epilogue:
//   branchless in-register row top-4 -> margin candidates -> EXACT fp32
//   re-score (identical math, rounds 2-13) -> softmax ->
//   out_row = sum_k attn_k * SVW[idx_k]   (fp32 gather, writes d_out direct)
// r14 algebra: retrieved @ Wout^T == sum_k attn_k * (SV@Wout^T)[idx_k].
// ---------------------------------------------------------------------------
__global__ __launch_bounds__(256)
void topk_refine(const unsigned short* __restrict__ scoresb,
                 const float* __restrict__ x,
                 const float* __restrict__ KW,
                 const float* __restrict__ SVW,
                 float* __restrict__ out) {
    const int tid  = threadIdx.x;
    const int lane = tid & 63;
    const int w    = tid >> 6;
    const int t    = blockIdx.x * 4 + w;
    const unsigned short* srow = scoresb + (size_t)t * NSLOTS;

    __shared__ int cand[4][CAND_MAX];
    __shared__ int ncand[4];

    // ---- load 64 bf16 scores/lane, build order-isomorphic packed keys
    unsigned int k[64];
#pragma unroll
    for (int j = 0; j < 8; ++j) {
        const int c0 = j * 512 + lane * 8;
        const u16x8 s8 = *(const u16x8*)(srow + c0);
#pragma unroll
        for (int e = 0; e < 8; ++e) {
            const unsigned int b   = (unsigned int)s8[e] & 0xffffu;
            const unsigned int ord = b ^ ((b & 0x8000u) ? 0xffffu : 0x8000u);
            k[j * 8 + e] = (ord << 12) | (4095u - (unsigned int)(c0 + e));
        }
    }

    // ---- branchless top-4 over the whole row
    unsigned int win[4];
#pragma unroll
    for (int p = 0; p < 4; ++p) {
        unsigned int a16[16];
#pragma unroll
        for (int e = 0; e < 16; ++e)
            a16[e] = max(max(k[e], k[e + 16]), max(k[e + 32], k[e + 48]));
        unsigned int a4[4];
#pragma unroll
        for (int e = 0; e < 4; ++e)
            a4[e] = max(max(a16[e], a16[e + 4]), max(a16[e + 8], a16[e + 12]));
        unsigned int m = max(max(a4[0], a4[1]), max(a4[2], a4[3]));
#pragma unroll
        for (int off = 1; off < 64; off <<= 1)
            m = max(m, (unsigned int)__shfl_xor((int)m, off));
        win[p] = m;
#pragma unroll
        for (int e = 0; e < 64; ++e) k[e] = (k[e] == m) ? 0u : k[e];
    }

    // decode 4th-best value -> threshold
    const unsigned int ord3 = win[3] >> 12;
    const unsigned int b3 =
        (ord3 & 0x8000u) ? (ord3 ^ 0x8000u) : (~ord3 & 0xffffu);
    const float thresh = bf2f((unsigned short)b3) - MARGIN;

    if (lane == 0) {
        ncand[w] = 4;
        cand[w][0] = 4095 - (int)(win[0] & 0xfffu);
        cand[w][1] = 4095 - (int)(win[1] & 0xfffu);
        cand[w][2] = 4095 - (int)(win[2] & 0xfffu);
        cand[w][3] = 4095 - (int)(win[3] & 0xfffu);
    }
    __syncthreads();

    // ---- margin candidates from remaining keys (masked keys decode NaN)
#pragma unroll
    for (int e = 0; e < 64; ++e) {
        const unsigned int kk  = k[e];
        const unsigned int ordv = kk >> 12;
        const unsigned int bv =
            (ordv & 0x8000u) ? (ordv ^ 0x8000u) : (~ordv & 0xffffu);
        if (bf2f((unsigned short)bv) >= thresh) {
            int p = atomicAdd(&ncand[w], 1);
            if (p < CAND_MAX) cand[w][p] = 4095 - (int)(kk & 0xfffu);
        }
    }
    __syncthreads();
    const int nc = min(ncand[w], CAND_MAX);

    // ---- exact fp32 re-score (IDENTICAL math to rounds 2-13 validated path)
    const float* xrow = x + (size_t)t * D_DIM + lane * 4;
    float4 xv[8];
#pragma unroll
    for (int i = 0; i < 8; ++i) xv[i] = *(const float4*)(xrow + 256 * i);

    float r0 = -INFINITY, r1 = -INFINITY, r2 = -INFINITY, r3 = -INFINITY;
    int   q0 = 0x7fffffff, q1 = 0x7fffffff, q2 = 0x7fffffff, q3 = 0x7fffffff;
    for (int c = 0; c < nc; ++c) {
        const int slot = cand[w][c];
        const float* kr = KW + (size_t)slot * D_DIM + lane * 4;
        float p = 0.0f;
#pragma unroll
        for (int i = 0; i < 8; ++i) {
            const float4 k4 = *(const float4*)(kr + 256 * i);
            p = fmaf(xv[i].x, k4.x, p);
            p = fmaf(xv[i].y, k4.y, p);
            p = fmaf(xv[i].z, k4.z, p);
            p = fmaf(xv[i].w, k4.w, p);
        }
#pragma unroll
        for (int off = 1; off < 64; off <<= 1) p += __shfl_xor(p, off);
        cand_insert(p, slot, r0, q0, r1, q1, r2, q2, r3, q3);
    }

    // ---- softmax over scaled top-4 (r0 is max)
    const float e1s = expf(SCALE * (r1 - r0));
    const float e2s = expf(SCALE * (r2 - r0));
    const float e3s = expf(SCALE * (r3 - r0));
    const float inv = 1.0f / (1.0f + e1s + e2s + e3s);
    const float w0s = inv, w1s = e1s * inv, w2s = e2s * inv, w3s = e3s * inv;

    // ---- gather fp32 SVW rows, weighted sum, write d_out directly
    const float* p0 = SVW + (size_t)q0 * D_DIM;
    const float* p1 = SVW + (size_t)q1 * D_DIM;
    const float* p2 = SVW + (size_t)q2 * D_DIM;
    const float* p3 = SVW + (size_t)q3 * D_DIM;
    float* orow = out + (size_t)t * D_DIM;
#pragma unroll
    for (int i = 0; i < 4; ++i) {
        const int d0 = lane * 8 + 512 * i;
        float4 a0 = *(const float4*)(p0 + d0), b0 = *(const float4*)(p0 + d0 + 4);
        float4 a1 = *(const float4*)(p1 + d0), b1 = *(const float4*)(p1 + d0 + 4);
        float4 a2 = *(const float4*)(p2 + d0), b2 = *(const float4*)(p2 + d0 + 4);
        float4 a3 = *(const float4*)(p3 + d0), b3v = *(const float4*)(p3 + d0 + 4);
        float4 oa, ob;
        oa.x = w0s * a0.x + w1s * a1.x + w2s * a2.x + w3s * a3.x;
        oa.y = w0s * a0.y + w1s * a1.y + w2s * a2.y + w3s * a3.y;
        oa.z = w0s * a0.z + w1s * a1.z + w2s * a2.z + w3s * a3.z;
        oa.w = w0s * a0.w + w1s * a1.w + w2s * a2.w + w3s * a3.w;
        ob.x = w0s * b0.x + w1s * b1.x + w2s * b2.x + w3s * b3v.x;
        ob.y = w0s * b0.y + w1s * b1.y + w2s * b2.y + w3s * b3v.y;
        ob.z = w0s * b0.z + w1s * b1.z + w2s * b2.z + w3s * b3v.z;
        ob.w = w0s * b0.w + w1s * b1.w + w2s * b2.w + w3s * b3v.w;
        *(float4*)(orow + d0)     = oa;
        *(float4*)(orow + d0 + 4) = ob;
    }
}

// ---------------------------------------------------------------------------
extern "C" void kernel_launch(void* const* d_in, const int* in_sizes, int n_in,
                              void* d_out, int out_size, void* d_ws, size_t ws_size,
                              hipStream_t stream) {
    const float* x    = (const float*)d_in[0];
    const float* sk   = (const float*)d_in[1];
    const float* sv   = (const float*)d_in[2];
    const float* wq   = (const float*)d_in[3];
    const float* wout = (const float*)d_in[4];

    // workspace layout (r1 proved ws >= 402.6 MB)
    char* base = (char*)d_ws;
    unsigned short* scoresb = (unsigned short*)base;              // 134.2 MB
    float*          KW      = (float*)(base + 134217728);         //  33.55 MB
    unsigned short* kwb     = (unsigned short*)(base + 167772160);//  16.78 MB
    unsigned short* woutb   = (unsigned short*)(base + 184549376);//   8.39 MB
    unsigned short* xb      = (unsigned short*)(base + 192937984);//  67.11 MB
    unsigned short* svb     = (unsigned short*)(base + 260046848);//  16.78 MB
    unsigned short* skh     = (unsigned short*)(base + 293601280);//  16.78 MB (dead after kw)
    unsigned short* skm     = (unsigned short*)(base + 310378496);//  16.78 MB (dead after kw)
    unsigned short* skl     = (unsigned short*)(base + 327155712);//  16.78 MB (dead after kw)
    unsigned short* wqth    = (unsigned short*)(base + 343932928);//   8.39 MB
    unsigned short* wqtm    = (unsigned short*)(base + 352321536);//   8.39 MB
    unsigned short* wqtl    = (unsigned short*)(base + 360710144);//   8.39 MB
    float*          SVW     = (float*)(base + 293601280);         //  33.55 MB (over skh/skm)

    const dim3 blk(256);

    // 3-way bf16 splits: SK (linear) and Wq (transposed)
    split3_lin<<<dim3((NSLOTS * (size_t)D_DIM) / 1024), blk, 0, stream>>>(
        sk, skh, skm, skl);
    split3_wqT<<<dim3(D_DIM / 32, D_DIM / 32), blk, 0, stream>>>(
        wq, wqth, wqtm, wqtl);

    // bf16 copies
    cvt_f32_bf16<<<dim3((BT_DIM * (size_t)D_DIM) / 2048), blk, 0, stream>>>(x, xb);
    cvt_f32_bf16<<<dim3((D_DIM * (size_t)D_DIM) / 2048), blk, 0, stream>>>(wout, woutb);
    cvt_f32_bf16<<<dim3((NSLOTS * (size_t)D_DIM) / 2048), blk, 0, stream>>>(sv, svb);

    // KW (fp32) + kwb (bf16) via 6-product split-bf16 MFMA (r12 validated)
    gemm_kw_mfma6<<<dim3(D_DIM / 128, NSLOTS / 128), blk, 0, stream>>>(
        skh, skm, skl, wqth, wqtm, wqtl, KW, kwb, NSLOTS, D_DIM, D_DIM);

    // SVW = SV @ Wout^T (fp32 out; 34 GF) -- launched AFTER kw (overwrites skh/skm)
    gemm_bf16_abt<false><<<dim3(D_DIM / 128, NSLOTS / 128), blk, 0, stream>>>(
        svb, woutb, SVW, NSLOTS, D_DIM, D_DIM);

    // approx scores (bf16 out) = xb @ kwb^T
    gemm_bf16_abt<true><<<dim3(NSLOTS / 128, BT_DIM / 128), blk, 0, stream>>>(
        xb, kwb, scoresb, BT_DIM, NSLOTS, D_DIM);

    // merged top-4 + exact refine + SVW gather -> writes d_out directly
    topk_refine<<<dim3(BT_DIM / 4), blk, 0, stream>>>(
        scoresb, x, KW, SVW, (float*)d_out);
}